// Round 2
// baseline (1260.733 us; speedup 1.0000x reference)
//
#include <hip/hip_runtime.h>

#define LN_EPS 1e-5f
#define SCAN_CHUNK 4096

typedef __bf16 bf16x8 __attribute__((ext_vector_type(8)));
typedef float f32x4 __attribute__((ext_vector_type(4)));

__device__ __forceinline__ float b2f(unsigned short s) {
    union { unsigned u; float f; } c; c.u = ((unsigned)s) << 16; return c.f;
}
__device__ __forceinline__ unsigned short f2b(float f) {
    union { float f; unsigned u; } c; c.f = f;
    unsigned r = (c.u + 0x7FFFu + ((c.u >> 16) & 1u)) >> 16;
    return (unsigned short)r;
}
__device__ __forceinline__ float leaky(float x) { return x >= 0.f ? x : 0.01f * x; }

// ---------------- CSR build ----------------

__global__ void init_kernel(int* ec, int* fill, int n) {
    int i = blockIdx.x * 256 + threadIdx.x;
    if (i < n) { ec[i] = 0; fill[i] = 0; }
}

__global__ void deg_kernel(const int* __restrict__ dst, int* ec, int e) {
    int i = blockIdx.x * 256 + threadIdx.x;
    if (i < e) atomicAdd(&ec[dst[i]], 1);
}

__global__ void scanA(const int* __restrict__ ec, int* __restrict__ bsum, int n) {
    __shared__ int red[4];
    int b = blockIdx.x, t = threadIdx.x;
    int base = b * SCAN_CHUNK + t * 16;
    int s = 0;
    #pragma unroll
    for (int k = 0; k < 16; ++k) { int i = base + k; if (i < n) s += ec[i]; }
    #pragma unroll
    for (int off = 32; off; off >>= 1) s += __shfl_down(s, off, 64);
    if ((t & 63) == 0) red[t >> 6] = s;
    __syncthreads();
    if (t == 0) bsum[b] = red[0] + red[1] + red[2] + red[3];
}

__global__ void scanB(int* bsum, int nb) {
    if (threadIdx.x == 0) {
        int acc = 0;
        for (int i = 0; i < nb; ++i) { int v = bsum[i]; bsum[i] = acc; acc += v; }
        bsum[nb] = acc;
    }
}

__global__ void scanC(const int* __restrict__ ec, const int* __restrict__ bsum,
                      int* __restrict__ ptr, int n, int nb) {
    __shared__ int wsum[4];
    int b = blockIdx.x, t = threadIdx.x, lane = t & 63, w = t >> 6;
    int base = b * SCAN_CHUNK + t * 16;
    int loc[16]; int s = 0;
    #pragma unroll
    for (int k = 0; k < 16; ++k) { int i = base + k; int v = (i < n) ? ec[i] : 0; loc[k] = s; s += v; }
    int x = s;
    #pragma unroll
    for (int off = 1; off < 64; off <<= 1) { int y = __shfl_up(x, off, 64); if (lane >= off) x += y; }
    if (lane == 63) wsum[w] = x;
    __syncthreads();
    int wexcl = 0;
    #pragma unroll
    for (int ww = 0; ww < 4; ++ww) if (ww < w) wexcl += wsum[ww];
    int toff = bsum[b] + wexcl + (x - s);
    #pragma unroll
    for (int k = 0; k < 16; ++k) { int i = base + k; if (i < n) ptr[i] = toff + loc[k]; }
    if (b == nb - 1 && t == 255) ptr[n] = bsum[nb];
}

__global__ void dinv_kernel(const int* __restrict__ ec, float* __restrict__ dinv, int n, int mpad) {
    int i = blockIdx.x * 256 + threadIdx.x;
    if (i < mpad) dinv[i] = (i < n) ? rsqrtf((float)(ec[i] + 1)) : 0.f;
}

__global__ void fill_kernel(const int* __restrict__ src, const int* __restrict__ dst,
                            const int* __restrict__ ptr, int* fill,
                            int* __restrict__ csrc, int e) {
    int i = blockIdx.x * 256 + threadIdx.x;
    if (i < e) {
        int d = dst[i];
        int pos = atomicAdd(&fill[d], 1);
        csrc[ptr[d] + pos] = src[i];
    }
}

// ---------------- weights: W^T in bf16 ----------------

__global__ void wt_kernel(const float* __restrict__ W1, const float* __restrict__ W2,
                          const float* __restrict__ W3, unsigned short* __restrict__ wt) {
    int k = blockIdx.x, l = blockIdx.y, nn = threadIdx.x;
    const float* W = (l == 0) ? W1 : (l == 1) ? W2 : W3;
    wt[l * 65536 + nn * 256 + k] = f2b(W[k * 256 + nn]);
}

// ---------------- layer 0: aggregate x (3 feats) then tiny matmul ----------------

__global__ void aggx_kernel(const float* __restrict__ x, const float* __restrict__ dinv,
                            const int* __restrict__ ptr, const int* __restrict__ csrc,
                            float* __restrict__ aggx, int n) {
    int i = blockIdx.x * 256 + threadIdx.x;
    if (i >= n) return;
    float di = dinv[i];
    float a0 = di * x[i * 3], a1 = di * x[i * 3 + 1], a2 = di * x[i * 3 + 2];
    int e0 = ptr[i], e1 = ptr[i + 1];
    for (int e = e0; e < e1; ++e) {
        int s = csrc[e]; float ds = dinv[s];
        a0 += ds * x[s * 3]; a1 += ds * x[s * 3 + 1]; a2 += ds * x[s * 3 + 2];
    }
    aggx[i * 3] = a0 * di; aggx[i * 3 + 1] = a1 * di; aggx[i * 3 + 2] = a2 * di;
}

__global__ __launch_bounds__(256) void h0_kernel(const float* __restrict__ aggx,
                          const float* __restrict__ W0, const float* __restrict__ b0,
                          float* __restrict__ h, unsigned short* __restrict__ hb,
                          int n, int mpad) {
    int t = threadIdx.x;
    int row = blockIdx.x * 4 + (t >> 6);
    int f = (t & 63) * 4;
    if (row >= mpad) return;
    size_t off = (size_t)row * 256 + f;
    if (row < n) {
        float a0 = aggx[row * 3], a1 = aggx[row * 3 + 1], a2 = aggx[row * 3 + 2];
        float4 w0 = *(const float4*)(W0 + f);
        float4 w1 = *(const float4*)(W0 + 256 + f);
        float4 w2 = *(const float4*)(W0 + 512 + f);
        float4 bb = *(const float4*)(b0 + f);
        float4 v;
        v.x = bb.x + a0 * w0.x + a1 * w1.x + a2 * w2.x;
        v.y = bb.y + a0 * w0.y + a1 * w1.y + a2 * w2.y;
        v.z = bb.z + a0 * w0.z + a1 * w1.z + a2 * w2.z;
        v.w = bb.w + a0 * w0.w + a1 * w1.w + a2 * w2.w;
        *(float4*)(h + off) = v;
        ushort4 o; o.x = f2b(v.x); o.y = f2b(v.y); o.z = f2b(v.z); o.w = f2b(v.w);
        *(ushort4*)(hb + off) = o;
    } else {
        ushort4 o; o.x = 0; o.y = 0; o.z = 0; o.w = 0;
        *(ushort4*)(hb + off) = o;
    }
}

// ---------------- GEMM: hwc[chunk][row][32] = dinv[row] * (hb @ W) ----------------

__global__ __launch_bounds__(256) void gemm_kernel(const unsigned short* __restrict__ A,
                                                   const unsigned short* __restrict__ Bt,
                                                   const float* __restrict__ dinv,
                                                   unsigned short* __restrict__ hwc,
                                                   int mpad) {
    const int K = 256;
    int wid = threadIdx.x >> 6, lane = threadIdx.x & 63;
    int m0 = blockIdx.x * 64;
    int n0 = wid * 64;
    int lr = lane & 15, lg = lane >> 4;
    f32x4 acc[4][4];
    #pragma unroll
    for (int i = 0; i < 4; i++)
        #pragma unroll
        for (int j = 0; j < 4; j++) acc[i][j] = (f32x4)(0.f);
    const unsigned short* Ap = A + (size_t)(m0 + lr) * K + lg * 8;
    const unsigned short* Bp = Bt + (size_t)(n0 + lr) * K + lg * 8;
    for (int kk = 0; kk < K; kk += 32) {
        bf16x8 af[4], bfr[4];
        #pragma unroll
        for (int mi = 0; mi < 4; mi++) {
            af[mi]  = *(const bf16x8*)(Ap + (size_t)mi * 16 * K + kk);
            bfr[mi] = *(const bf16x8*)(Bp + (size_t)mi * 16 * K + kk);
        }
        #pragma unroll
        for (int mi = 0; mi < 4; mi++)
            #pragma unroll
            for (int ni = 0; ni < 4; ni++)
                acc[mi][ni] = __builtin_amdgcn_mfma_f32_16x16x32_bf16(af[mi], bfr[ni], acc[mi][ni], 0, 0, 0);
    }
    #pragma unroll
    for (int mi = 0; mi < 4; mi++) {
        int r0 = m0 + mi * 16 + lg * 4;
        float4 dv = *(const float4*)(dinv + r0);
        #pragma unroll
        for (int ni = 0; ni < 4; ni++) {
            int c = n0 + ni * 16 + lr;
            int ch = c >> 5, cf = c & 31;
            unsigned short* dp = hwc + ((size_t)ch * mpad + r0) * 32 + cf;
            dp[0]  = f2b(acc[mi][ni][0] * dv.x);
            dp[32] = f2b(acc[mi][ni][1] * dv.y);
            dp[64] = f2b(acc[mi][ni][2] * dv.z);
            dp[96] = f2b(acc[mi][ni][3] * dv.w);
        }
    }
}

// ---------------- SpMM gather (XCD feature-chunked) ----------------

__global__ __launch_bounds__(256) void spmm_kernel(
    const unsigned short* __restrict__ hwc,
    const int* __restrict__ ptr, const int* __restrict__ csrc,
    const float* __restrict__ dinv, const float* __restrict__ bias,
    float* __restrict__ h, unsigned short* __restrict__ hb,
    int n, int mpad, int write_hb) {
    int chunk = blockIdx.x & 7;   // one feature-chunk per XCD (round-robin dispatch)
    int g = blockIdx.x >> 3;
    int wid = threadIdx.x >> 6, lane = threadIdx.x & 63;
    int half = lane >> 5, f = lane & 31;
    const unsigned short* base = hwc + (size_t)chunk * mpad * 32 + f;
    float bv = bias[chunk * 32 + f];
    int node0 = (g * 4 + wid) * 4;
    for (int k = 0; k < 4; ++k) {
        int node = node0 + k;
        if (node >= n) return;
        float acc = (half == 0) ? b2f(base[(size_t)node * 32]) : 0.f;  // self term
        int e0 = ptr[node], e1 = ptr[node + 1];
        int e = e0 + half;
        int s_nxt = (e < e1) ? __builtin_nontemporal_load(csrc + e) : 0;
        while (e < e1) {
            int s = s_nxt;
            int e2 = e + 2;
            if (e2 < e1) s_nxt = __builtin_nontemporal_load(csrc + e2);
            acc += b2f(base[(size_t)s * 32]);
            e = e2;
        }
        acc += __shfl_xor(acc, 32, 64);
        if (half == 0) {
            size_t off = (size_t)node * 256 + chunk * 32 + f;
            float r = leaky(dinv[node] * acc + bv) + __builtin_nontemporal_load(h + off);
            __builtin_nontemporal_store(r, h + off);
            if (write_hb) __builtin_nontemporal_store(f2b(r), hb + off);
        }
    }
}

// ---------------- segment max pooling ----------------

__global__ __launch_bounds__(256) void pool_kernel(const float* __restrict__ h,
                                                   const int* __restrict__ batch,
                                                   float* __restrict__ pooled, int n) {
    int b = blockIdx.x, d = threadIdx.x;
    int lo = 0, hi = n;
    while (lo < hi) { int m = (lo + hi) >> 1; if (batch[m] < b) lo = m + 1; else hi = m; }
    int s = lo;
    lo = 0; hi = n;
    while (lo < hi) { int m = (lo + hi) >> 1; if (batch[m] < b + 1) lo = m + 1; else hi = m; }
    int e = lo;
    float mx = -3.402823466e38f;
    for (int r = s; r < e; ++r) mx = fmaxf(mx, h[(size_t)r * 256 + d]);
    pooled[(size_t)b * 256 + d] = mx;
}

// ---------------- head ----------------

__device__ __forceinline__ float blk_sum(float v, float* red) {
    #pragma unroll
    for (int off = 32; off; off >>= 1) v += __shfl_down(v, off, 64);
    int lane = threadIdx.x & 63, wid = threadIdx.x >> 6;
    if (lane == 0) red[wid] = v;
    __syncthreads();
    float s = red[0] + red[1] + red[2] + red[3];
    __syncthreads();
    return s;
}

__global__ __launch_bounds__(256) void head_kernel(
    const float* __restrict__ pooled, const float* __restrict__ a,
    const float* __restrict__ afc1_w, const float* __restrict__ afc1_b,
    const float* __restrict__ afc2_w, const float* __restrict__ afc2_b,
    const float* __restrict__ afc3_w, const float* __restrict__ afc3_b,
    const float* __restrict__ fc1_w, const float* __restrict__ fc1_b,
    const float* __restrict__ fc2_w, const float* __restrict__ fc2_b,
    const float* __restrict__ ln1_g, const float* __restrict__ ln1_b,
    const float* __restrict__ ln2_g, const float* __restrict__ ln2_b,
    const float* __restrict__ ln4_g, const float* __restrict__ ln4_b,
    const float* __restrict__ ln5_g, const float* __restrict__ ln5_b,
    float* __restrict__ out) {
    __shared__ float red[4];
    __shared__ float sM[2];
    __shared__ float s1[56], s2[56], sZ[256], sT[64];
    int b = blockIdx.x, tid = threadIdx.x;

    float pv = pooled[(size_t)b * 256 + tid];
    float m = blk_sum(pv, red) * (1.f / 256.f);
    float d0 = pv - m;
    float var = blk_sum(d0 * d0, red) * (1.f / 256.f);
    float V = d0 * rsqrtf(var + LN_EPS) * ln2_g[tid] + ln2_b[tid];

    if (tid < 56) {
        float acc = afc1_b[tid];
        #pragma unroll
        for (int k = 0; k < 7; ++k) acc += a[b * 7 + k] * afc1_w[k * 56 + tid];
        s1[tid] = leaky(acc);
    }
    __syncthreads();
    if (tid == 0) {
        float s = 0.f; for (int k = 0; k < 56; ++k) s += s1[k];
        float mm = s / 56.f;
        float q = 0.f; for (int k = 0; k < 56; ++k) { float d = s1[k] - mm; q += d * d; }
        sM[0] = mm; sM[1] = rsqrtf(q / 56.f + LN_EPS);
    }
    __syncthreads();
    if (tid < 56) s1[tid] = (s1[tid] - sM[0]) * sM[1] * ln5_g[tid] + ln5_b[tid];
    __syncthreads();
    if (tid < 56) {
        float acc = afc2_b[tid];
        for (int k = 0; k < 56; ++k) acc += s1[k] * afc2_w[k * 56 + tid];
        s2[tid] = leaky(acc);
    }
    __syncthreads();
    float acc = afc3_b[tid];
    for (int k = 0; k < 56; ++k) acc += s2[k] * afc3_w[k * 256 + tid];
    acc = leaky(acc);
    m = blk_sum(acc, red) * (1.f / 256.f);
    d0 = acc - m;
    var = blk_sum(d0 * d0, red) * (1.f / 256.f);
    float av = d0 * rsqrtf(var + LN_EPS) * ln1_g[tid] + ln1_b[tid];

    float z = V * av;
    sZ[tid] = z;
    __syncthreads();
    if (tid < 64) {
        float a2 = fc1_b[tid];
        for (int k = 0; k < 256; ++k) a2 += sZ[k] * fc1_w[k * 64 + tid];
        sT[tid] = leaky(a2);
    }
    __syncthreads();
    if (tid == 0) {
        float s = 0.f; for (int k = 0; k < 64; ++k) s += sT[k];
        float mm = s / 64.f;
        float q = 0.f; for (int k = 0; k < 64; ++k) { float d = sT[k] - mm; q += d * d; }
        float r = rsqrtf(q / 64.f + LN_EPS);
        float o = fc2_b[0];
        for (int k = 0; k < 64; ++k) {
            float zz = (sT[k] - mm) * r * ln4_g[k] + ln4_b[k];
            o += zz * fc2_w[k];
        }
        out[b] = o;
    }
}

// ---------------- launch ----------------

extern "C" void kernel_launch(void* const* d_in, const int* in_sizes, int n_in,
                              void* d_out, int out_size, void* d_ws, size_t ws_size,
                              hipStream_t stream) {
    const float* x     = (const float*)d_in[0];
    const int*   eidx  = (const int*)d_in[1];
    const int*   batch = (const int*)d_in[2];
    const float* a     = (const float*)d_in[3];
    const float* W0 = (const float*)d_in[4];  const float* b0 = (const float*)d_in[5];
    const float* W1 = (const float*)d_in[6];  const float* b1 = (const float*)d_in[7];
    const float* W2 = (const float*)d_in[8];  const float* b2 = (const float*)d_in[9];
    const float* W3 = (const float*)d_in[10]; const float* b3 = (const float*)d_in[11];
    const float* afc1_w = (const float*)d_in[12]; const float* afc1_b = (const float*)d_in[13];
    const float* afc2_w = (const float*)d_in[14]; const float* afc2_b = (const float*)d_in[15];
    const float* afc3_w = (const float*)d_in[16]; const float* afc3_b = (const float*)d_in[17];
    const float* fc1_w  = (const float*)d_in[18]; const float* fc1_b  = (const float*)d_in[19];
    const float* fc2_w  = (const float*)d_in[20]; const float* fc2_b  = (const float*)d_in[21];
    const float* ln1_g = (const float*)d_in[22]; const float* ln1_b = (const float*)d_in[23];
    const float* ln2_g = (const float*)d_in[24]; const float* ln2_b = (const float*)d_in[25];
    const float* ln4_g = (const float*)d_in[26]; const float* ln4_b = (const float*)d_in[27];
    const float* ln5_g = (const float*)d_in[28]; const float* ln5_b = (const float*)d_in[29];

    int N = in_sizes[0] / 3;
    int E = in_sizes[1] / 2;
    int B = in_sizes[3] / 7;
    int Mpad = ((N + 63) / 64) * 64;
    int NB = (N + SCAN_CHUNK - 1) / SCAN_CHUNK;

    char* p = (char*)d_ws;
    auto alloc = [&](size_t bytes) -> char* {
        char* r = p; p += (bytes + 255) & ~(size_t)255; return r;
    };
    int*   ec   = (int*)alloc((size_t)N * 4);
    int*   fill = (int*)alloc((size_t)N * 4);
    int*   ptr  = (int*)alloc((size_t)(N + 1) * 4);
    int*   bsum = (int*)alloc((size_t)(NB + 1) * 4);
    int*   csrc = (int*)alloc((size_t)E * 4);
    float* dinv = (float*)alloc((size_t)Mpad * 4);
    float* aggx = (float*)alloc((size_t)N * 3 * 4);
    float* h    = (float*)alloc((size_t)N * 256 * 4);
    unsigned short* hb  = (unsigned short*)alloc((size_t)Mpad * 256 * 2);
    unsigned short* hwc = (unsigned short*)alloc((size_t)Mpad * 256 * 2);  // [8][Mpad][32]
    unsigned short* wt  = (unsigned short*)alloc((size_t)3 * 65536 * 2);
    float* pooled = (float*)alloc((size_t)B * 256 * 4);

    const int* srcl = eidx;
    const int* dstl = eidx + E;

    init_kernel<<<(N + 255) / 256, 256, 0, stream>>>(ec, fill, N);
    deg_kernel<<<(E + 255) / 256, 256, 0, stream>>>(dstl, ec, E);
    scanA<<<NB, 256, 0, stream>>>(ec, bsum, N);
    scanB<<<1, 64, 0, stream>>>(bsum, NB);
    scanC<<<NB, 256, 0, stream>>>(ec, bsum, ptr, N, NB);
    dinv_kernel<<<(Mpad + 255) / 256, 256, 0, stream>>>(ec, dinv, N, Mpad);
    fill_kernel<<<(E + 255) / 256, 256, 0, stream>>>(srcl, dstl, ptr, fill, csrc, E);
    wt_kernel<<<dim3(256, 3), 256, 0, stream>>>(W1, W2, W3, wt);
    aggx_kernel<<<(N + 255) / 256, 256, 0, stream>>>(x, dinv, ptr, csrc, aggx, N);
    h0_kernel<<<Mpad / 4, 256, 0, stream>>>(aggx, W0, b0, h, hb, N, Mpad);

    const float* biases[3] = { b1, b2, b3 };
    int ngrp = (N + 15) / 16;
    for (int l = 0; l < 3; ++l) {
        gemm_kernel<<<Mpad / 64, 256, 0, stream>>>(hb, wt + (size_t)l * 65536, dinv, hwc, Mpad);
        spmm_kernel<<<ngrp * 8, 256, 0, stream>>>(hwc, ptr, csrc, dinv, biases[l],
                                                  h, hb, N, Mpad, (l < 2) ? 1 : 0);
    }

    pool_kernel<<<B, 256, 0, stream>>>(h, batch, pooled, N);
    head_kernel<<<B, 256, 0, stream>>>(pooled, a,
        afc1_w, afc1_b, afc2_w, afc2_b, afc3_w, afc3_b,
        fc1_w, fc1_b, fc2_w, fc2_b,
        ln1_g, ln1_b, ln2_g, ln2_b, ln4_g, ln4_b, ln5_g, ln5_b,
        (float*)d_out);
}

// Round 3
// 661.175 us; speedup vs baseline: 1.9068x; 1.9068x over previous
//
#include <hip/hip_runtime.h>

#define LN_EPS 1e-5f
#define SCAN_CHUNK 4096

typedef __bf16 bf16x8 __attribute__((ext_vector_type(8)));
typedef float f32x4 __attribute__((ext_vector_type(4)));

__device__ __forceinline__ float b2f(unsigned short s) {
    union { unsigned u; float f; } c; c.u = ((unsigned)s) << 16; return c.f;
}
__device__ __forceinline__ float blo(unsigned v) {
    union { unsigned u; float f; } c; c.u = v << 16; return c.f;
}
__device__ __forceinline__ float bhi(unsigned v) {
    union { unsigned u; float f; } c; c.u = v & 0xffff0000u; return c.f;
}
__device__ __forceinline__ unsigned short f2b(float f) {
    union { float f; unsigned u; } c; c.f = f;
    unsigned r = (c.u + 0x7FFFu + ((c.u >> 16) & 1u)) >> 16;
    return (unsigned short)r;
}
__device__ __forceinline__ float leaky(float x) { return x >= 0.f ? x : 0.01f * x; }

// ---------------- CSR build ----------------

__global__ void init_kernel(int* ec, int* fill, int n) {
    int i = blockIdx.x * 256 + threadIdx.x;
    if (i < n) { ec[i] = 0; fill[i] = 0; }
}

__global__ void deg_kernel(const int* __restrict__ dst, int* ec, int e) {
    int i = blockIdx.x * 256 + threadIdx.x;
    if (i < e) atomicAdd(&ec[dst[i]], 1);
}

__global__ void scanA(const int* __restrict__ ec, int* __restrict__ bsum, int n) {
    __shared__ int red[4];
    int b = blockIdx.x, t = threadIdx.x;
    int base = b * SCAN_CHUNK + t * 16;
    int s = 0;
    #pragma unroll
    for (int k = 0; k < 16; ++k) { int i = base + k; if (i < n) s += ec[i]; }
    #pragma unroll
    for (int off = 32; off; off >>= 1) s += __shfl_down(s, off, 64);
    if ((t & 63) == 0) red[t >> 6] = s;
    __syncthreads();
    if (t == 0) bsum[b] = red[0] + red[1] + red[2] + red[3];
}

__global__ void scanB(int* bsum, int nb) {
    if (threadIdx.x == 0) {
        int acc = 0;
        for (int i = 0; i < nb; ++i) { int v = bsum[i]; bsum[i] = acc; acc += v; }
        bsum[nb] = acc;
    }
}

__global__ void scanC(const int* __restrict__ ec, const int* __restrict__ bsum,
                      int* __restrict__ ptr, int n, int nb) {
    __shared__ int wsum[4];
    int b = blockIdx.x, t = threadIdx.x, lane = t & 63, w = t >> 6;
    int base = b * SCAN_CHUNK + t * 16;
    int loc[16]; int s = 0;
    #pragma unroll
    for (int k = 0; k < 16; ++k) { int i = base + k; int v = (i < n) ? ec[i] : 0; loc[k] = s; s += v; }
    int x = s;
    #pragma unroll
    for (int off = 1; off < 64; off <<= 1) { int y = __shfl_up(x, off, 64); if (lane >= off) x += y; }
    if (lane == 63) wsum[w] = x;
    __syncthreads();
    int wexcl = 0;
    #pragma unroll
    for (int ww = 0; ww < 4; ++ww) if (ww < w) wexcl += wsum[ww];
    int toff = bsum[b] + wexcl + (x - s);
    #pragma unroll
    for (int k = 0; k < 16; ++k) { int i = base + k; if (i < n) ptr[i] = toff + loc[k]; }
    if (b == nb - 1 && t == 255) ptr[n] = bsum[nb];
}

__global__ void dinv_kernel(const int* __restrict__ ec, float* __restrict__ dinv, int n, int mpad) {
    int i = blockIdx.x * 256 + threadIdx.x;
    if (i < mpad) dinv[i] = (i < n) ? rsqrtf((float)(ec[i] + 1)) : 0.f;
}

__global__ void fill_kernel(const int* __restrict__ src, const int* __restrict__ dst,
                            const int* __restrict__ ptr, int* fill,
                            int* __restrict__ csrc, int e) {
    int i = blockIdx.x * 256 + threadIdx.x;
    if (i < e) {
        int d = dst[i];
        int pos = atomicAdd(&fill[d], 1);
        csrc[ptr[d] + pos] = src[i];
    }
}

// ---------------- weights: W^T in bf16 ----------------

__global__ void wt_kernel(const float* __restrict__ W1, const float* __restrict__ W2,
                          const float* __restrict__ W3, unsigned short* __restrict__ wt) {
    int k = blockIdx.x, l = blockIdx.y, nn = threadIdx.x;
    const float* W = (l == 0) ? W1 : (l == 1) ? W2 : W3;
    wt[l * 65536 + nn * 256 + k] = f2b(W[k * 256 + nn]);
}

// ---------------- layer 0: aggregate x (3 feats) then tiny matmul ----------------

__global__ void aggx_kernel(const float* __restrict__ x, const float* __restrict__ dinv,
                            const int* __restrict__ ptr, const int* __restrict__ csrc,
                            float* __restrict__ aggx, int n) {
    int i = blockIdx.x * 256 + threadIdx.x;
    if (i >= n) return;
    float di = dinv[i];
    float a0 = di * x[i * 3], a1 = di * x[i * 3 + 1], a2 = di * x[i * 3 + 2];
    float p0 = 0.f, p1 = 0.f, p2 = 0.f;
    float q0 = 0.f, q1 = 0.f, q2 = 0.f;
    float r0 = 0.f, r1 = 0.f, r2 = 0.f;
    int e0 = ptr[i], e1 = ptr[i + 1];
    int e = e0;
    for (; e + 4 <= e1; e += 4) {
        int s0 = csrc[e], s1 = csrc[e + 1], s2 = csrc[e + 2], s3 = csrc[e + 3];
        float d0 = dinv[s0], d1 = dinv[s1], d2 = dinv[s2], d3 = dinv[s3];
        a0 += d0 * x[s0 * 3]; a1 += d0 * x[s0 * 3 + 1]; a2 += d0 * x[s0 * 3 + 2];
        p0 += d1 * x[s1 * 3]; p1 += d1 * x[s1 * 3 + 1]; p2 += d1 * x[s1 * 3 + 2];
        q0 += d2 * x[s2 * 3]; q1 += d2 * x[s2 * 3 + 1]; q2 += d2 * x[s2 * 3 + 2];
        r0 += d3 * x[s3 * 3]; r1 += d3 * x[s3 * 3 + 1]; r2 += d3 * x[s3 * 3 + 2];
    }
    for (; e < e1; ++e) {
        int s = csrc[e]; float ds = dinv[s];
        a0 += ds * x[s * 3]; a1 += ds * x[s * 3 + 1]; a2 += ds * x[s * 3 + 2];
    }
    a0 += (p0 + q0) + r0; a1 += (p1 + q1) + r1; a2 += (p2 + q2) + r2;
    aggx[i * 3] = a0 * di; aggx[i * 3 + 1] = a1 * di; aggx[i * 3 + 2] = a2 * di;
}

__global__ __launch_bounds__(256) void h0_kernel(const float* __restrict__ aggx,
                          const float* __restrict__ W0, const float* __restrict__ b0,
                          float* __restrict__ h, unsigned short* __restrict__ hb,
                          int n, int mpad) {
    int t = threadIdx.x;
    int row = blockIdx.x * 4 + (t >> 6);
    int f = (t & 63) * 4;
    if (row >= mpad) return;
    size_t off = (size_t)row * 256 + f;
    if (row < n) {
        float a0 = aggx[row * 3], a1 = aggx[row * 3 + 1], a2 = aggx[row * 3 + 2];
        float4 w0 = *(const float4*)(W0 + f);
        float4 w1 = *(const float4*)(W0 + 256 + f);
        float4 w2 = *(const float4*)(W0 + 512 + f);
        float4 bb = *(const float4*)(b0 + f);
        float4 v;
        v.x = bb.x + a0 * w0.x + a1 * w1.x + a2 * w2.x;
        v.y = bb.y + a0 * w0.y + a1 * w1.y + a2 * w2.y;
        v.z = bb.z + a0 * w0.z + a1 * w1.z + a2 * w2.z;
        v.w = bb.w + a0 * w0.w + a1 * w1.w + a2 * w2.w;
        *(float4*)(h + off) = v;
        ushort4 o; o.x = f2b(v.x); o.y = f2b(v.y); o.z = f2b(v.z); o.w = f2b(v.w);
        *(ushort4*)(hb + off) = o;
    } else {
        ushort4 o; o.x = 0; o.y = 0; o.z = 0; o.w = 0;
        *(ushort4*)(hb + off) = o;
    }
}

// ---------------- GEMM: hwc[chunk][row][32] = dinv[row] * (hb @ W) ----------------

__global__ __launch_bounds__(256) void gemm_kernel(const unsigned short* __restrict__ A,
                                                   const unsigned short* __restrict__ Bt,
                                                   const float* __restrict__ dinv,
                                                   unsigned short* __restrict__ hwc,
                                                   int mpad) {
    const int K = 256;
    int wid = threadIdx.x >> 6, lane = threadIdx.x & 63;
    int m0 = blockIdx.x * 64;
    int n0 = wid * 64;
    int lr = lane & 15, lg = lane >> 4;
    f32x4 acc[4][4];
    #pragma unroll
    for (int i = 0; i < 4; i++)
        #pragma unroll
        for (int j = 0; j < 4; j++) acc[i][j] = (f32x4)(0.f);
    const unsigned short* Ap = A + (size_t)(m0 + lr) * K + lg * 8;
    const unsigned short* Bp = Bt + (size_t)(n0 + lr) * K + lg * 8;
    for (int kk = 0; kk < K; kk += 32) {
        bf16x8 af[4], bfr[4];
        #pragma unroll
        for (int mi = 0; mi < 4; mi++) {
            af[mi]  = *(const bf16x8*)(Ap + (size_t)mi * 16 * K + kk);
            bfr[mi] = *(const bf16x8*)(Bp + (size_t)mi * 16 * K + kk);
        }
        #pragma unroll
        for (int mi = 0; mi < 4; mi++)
            #pragma unroll
            for (int ni = 0; ni < 4; ni++)
                acc[mi][ni] = __builtin_amdgcn_mfma_f32_16x16x32_bf16(af[mi], bfr[ni], acc[mi][ni], 0, 0, 0);
    }
    #pragma unroll
    for (int mi = 0; mi < 4; mi++) {
        int r0 = m0 + mi * 16 + lg * 4;
        float4 dv = *(const float4*)(dinv + r0);
        #pragma unroll
        for (int ni = 0; ni < 4; ni++) {
            int c = n0 + ni * 16 + lr;
            int ch = c >> 5, cf = c & 31;
            unsigned short* dp = hwc + ((size_t)ch * mpad + r0) * 32 + cf;
            dp[0]  = f2b(acc[mi][ni][0] * dv.x);
            dp[32] = f2b(acc[mi][ni][1] * dv.y);
            dp[64] = f2b(acc[mi][ni][2] * dv.z);
            dp[96] = f2b(acc[mi][ni][3] * dv.w);
        }
    }
}

// ---------------- SpMM gather (XCD feature-chunked, 4 nodes/wave, 4-deep unroll) ----------------

__global__ __launch_bounds__(256) void spmm_kernel(
    const unsigned short* __restrict__ hwc,
    const int* __restrict__ ptr, const int* __restrict__ csrc,
    const float* __restrict__ dinv, const float* __restrict__ bias,
    float* __restrict__ h, unsigned short* __restrict__ hb,
    int n, int mpad, int write_hb) {
    int chunk = blockIdx.x & 7;   // chunk pinned to XCD (round-robin dispatch)
    int g = blockIdx.x >> 3;
    int t = threadIdx.x;
    int node = g * 16 + (t >> 4);
    if (node >= n) return;
    int fl = t & 15;
    const char* cb = (const char*)(hwc + (size_t)chunk * mpad * 32);
    unsigned loff = (unsigned)(fl << 2);
    int e0 = ptr[node], e1 = ptr[node + 1];
    unsigned sv = *(const unsigned*)(cb + (((unsigned)node << 6) | loff));
    float a0 = blo(sv), a1 = bhi(sv);
    float p0 = 0.f, p1 = 0.f, q0 = 0.f, q1 = 0.f, r0 = 0.f, r1 = 0.f;
    int e = e0;
    for (; e + 4 <= e1; e += 4) {
        int s0 = csrc[e], s1 = csrc[e + 1], s2 = csrc[e + 2], s3 = csrc[e + 3];
        unsigned v0 = *(const unsigned*)(cb + (((unsigned)s0 << 6) | loff));
        unsigned v1 = *(const unsigned*)(cb + (((unsigned)s1 << 6) | loff));
        unsigned v2 = *(const unsigned*)(cb + (((unsigned)s2 << 6) | loff));
        unsigned v3 = *(const unsigned*)(cb + (((unsigned)s3 << 6) | loff));
        a0 += blo(v0); a1 += bhi(v0);
        p0 += blo(v1); p1 += bhi(v1);
        q0 += blo(v2); q1 += bhi(v2);
        r0 += blo(v3); r1 += bhi(v3);
    }
    for (; e < e1; ++e) {
        int s = csrc[e];
        unsigned v = *(const unsigned*)(cb + (((unsigned)s << 6) | loff));
        a0 += blo(v); a1 += bhi(v);
    }
    a0 += (p0 + q0) + r0;
    a1 += (p1 + q1) + r1;
    float di = dinv[node];
    float bv0 = bias[chunk * 32 + fl * 2];
    float bv1 = bias[chunk * 32 + fl * 2 + 1];
    size_t off = (size_t)node * 256 + chunk * 32 + fl * 2;
    float h0v = __builtin_nontemporal_load(h + off);
    float h1v = __builtin_nontemporal_load(h + off + 1);
    float o0 = leaky(di * a0 + bv0) + h0v;
    float o1 = leaky(di * a1 + bv1) + h1v;
    __builtin_nontemporal_store(o0, h + off);
    __builtin_nontemporal_store(o1, h + off + 1);
    if (write_hb) {
        unsigned ob = ((unsigned)f2b(o1) << 16) | (unsigned)f2b(o0);
        __builtin_nontemporal_store(ob, (unsigned*)(hb + off));
    }
}

// ---------------- segment max pooling ----------------

__global__ __launch_bounds__(256) void pool_kernel(const float* __restrict__ h,
                                                   const int* __restrict__ batch,
                                                   float* __restrict__ pooled, int n) {
    int b = blockIdx.x, d = threadIdx.x;
    int lo = 0, hi = n;
    while (lo < hi) { int m = (lo + hi) >> 1; if (batch[m] < b) lo = m + 1; else hi = m; }
    int s = lo;
    lo = 0; hi = n;
    while (lo < hi) { int m = (lo + hi) >> 1; if (batch[m] < b + 1) lo = m + 1; else hi = m; }
    int e = lo;
    float mx = -3.402823466e38f;
    for (int r = s; r < e; ++r) mx = fmaxf(mx, h[(size_t)r * 256 + d]);
    pooled[(size_t)b * 256 + d] = mx;
}

// ---------------- head ----------------

__device__ __forceinline__ float blk_sum(float v, float* red) {
    #pragma unroll
    for (int off = 32; off; off >>= 1) v += __shfl_down(v, off, 64);
    int lane = threadIdx.x & 63, wid = threadIdx.x >> 6;
    if (lane == 0) red[wid] = v;
    __syncthreads();
    float s = red[0] + red[1] + red[2] + red[3];
    __syncthreads();
    return s;
}

__global__ __launch_bounds__(256) void head_kernel(
    const float* __restrict__ pooled, const float* __restrict__ a,
    const float* __restrict__ afc1_w, const float* __restrict__ afc1_b,
    const float* __restrict__ afc2_w, const float* __restrict__ afc2_b,
    const float* __restrict__ afc3_w, const float* __restrict__ afc3_b,
    const float* __restrict__ fc1_w, const float* __restrict__ fc1_b,
    const float* __restrict__ fc2_w, const float* __restrict__ fc2_b,
    const float* __restrict__ ln1_g, const float* __restrict__ ln1_b,
    const float* __restrict__ ln2_g, const float* __restrict__ ln2_b,
    const float* __restrict__ ln4_g, const float* __restrict__ ln4_b,
    const float* __restrict__ ln5_g, const float* __restrict__ ln5_b,
    float* __restrict__ out) {
    __shared__ float red[4];
    __shared__ float sM[2];
    __shared__ float s1[56], s2[56], sZ[256], sT[64];
    int b = blockIdx.x, tid = threadIdx.x;

    float pv = pooled[(size_t)b * 256 + tid];
    float m = blk_sum(pv, red) * (1.f / 256.f);
    float d0 = pv - m;
    float var = blk_sum(d0 * d0, red) * (1.f / 256.f);
    float V = d0 * rsqrtf(var + LN_EPS) * ln2_g[tid] + ln2_b[tid];

    if (tid < 56) {
        float acc = afc1_b[tid];
        #pragma unroll
        for (int k = 0; k < 7; ++k) acc += a[b * 7 + k] * afc1_w[k * 56 + tid];
        s1[tid] = leaky(acc);
    }
    __syncthreads();
    if (tid == 0) {
        float s = 0.f; for (int k = 0; k < 56; ++k) s += s1[k];
        float mm = s / 56.f;
        float q = 0.f; for (int k = 0; k < 56; ++k) { float d = s1[k] - mm; q += d * d; }
        sM[0] = mm; sM[1] = rsqrtf(q / 56.f + LN_EPS);
    }
    __syncthreads();
    if (tid < 56) s1[tid] = (s1[tid] - sM[0]) * sM[1] * ln5_g[tid] + ln5_b[tid];
    __syncthreads();
    if (tid < 56) {
        float acc = afc2_b[tid];
        for (int k = 0; k < 56; ++k) acc += s1[k] * afc2_w[k * 56 + tid];
        s2[tid] = leaky(acc);
    }
    __syncthreads();
    float acc = afc3_b[tid];
    for (int k = 0; k < 56; ++k) acc += s2[k] * afc3_w[k * 256 + tid];
    acc = leaky(acc);
    m = blk_sum(acc, red) * (1.f / 256.f);
    d0 = acc - m;
    var = blk_sum(d0 * d0, red) * (1.f / 256.f);
    float av = d0 * rsqrtf(var + LN_EPS) * ln1_g[tid] + ln1_b[tid];

    float z = V * av;
    sZ[tid] = z;
    __syncthreads();
    if (tid < 64) {
        float a2 = fc1_b[tid];
        for (int k = 0; k < 256; ++k) a2 += sZ[k] * fc1_w[k * 64 + tid];
        sT[tid] = leaky(a2);
    }
    __syncthreads();
    if (tid == 0) {
        float s = 0.f; for (int k = 0; k < 64; ++k) s += sT[k];
        float mm = s / 64.f;
        float q = 0.f; for (int k = 0; k < 64; ++k) { float d = sT[k] - mm; q += d * d; }
        float r = rsqrtf(q / 64.f + LN_EPS);
        float o = fc2_b[0];
        for (int k = 0; k < 64; ++k) {
            float zz = (sT[k] - mm) * r * ln4_g[k] + ln4_b[k];
            o += zz * fc2_w[k];
        }
        out[b] = o;
    }
}

// ---------------- launch ----------------

extern "C" void kernel_launch(void* const* d_in, const int* in_sizes, int n_in,
                              void* d_out, int out_size, void* d_ws, size_t ws_size,
                              hipStream_t stream) {
    const float* x     = (const float*)d_in[0];
    const int*   eidx  = (const int*)d_in[1];
    const int*   batch = (const int*)d_in[2];
    const float* a     = (const float*)d_in[3];
    const float* W0 = (const float*)d_in[4];  const float* b0 = (const float*)d_in[5];
    const float* W1 = (const float*)d_in[6];  const float* b1 = (const float*)d_in[7];
    const float* W2 = (const float*)d_in[8];  const float* b2 = (const float*)d_in[9];
    const float* W3 = (const float*)d_in[10]; const float* b3 = (const float*)d_in[11];
    const float* afc1_w = (const float*)d_in[12]; const float* afc1_b = (const float*)d_in[13];
    const float* afc2_w = (const float*)d_in[14]; const float* afc2_b = (const float*)d_in[15];
    const float* afc3_w = (const float*)d_in[16]; const float* afc3_b = (const float*)d_in[17];
    const float* fc1_w  = (const float*)d_in[18]; const float* fc1_b  = (const float*)d_in[19];
    const float* fc2_w  = (const float*)d_in[20]; const float* fc2_b  = (const float*)d_in[21];
    const float* ln1_g = (const float*)d_in[22]; const float* ln1_b = (const float*)d_in[23];
    const float* ln2_g = (const float*)d_in[24]; const float* ln2_b = (const float*)d_in[25];
    const float* ln4_g = (const float*)d_in[26]; const float* ln4_b = (const float*)d_in[27];
    const float* ln5_g = (const float*)d_in[28]; const float* ln5_b = (const float*)d_in[29];

    int N = in_sizes[0] / 3;
    int E = in_sizes[1] / 2;
    int B = in_sizes[3] / 7;
    int Mpad = ((N + 63) / 64) * 64;
    int NB = (N + SCAN_CHUNK - 1) / SCAN_CHUNK;

    char* p = (char*)d_ws;
    auto alloc = [&](size_t bytes) -> char* {
        char* r = p; p += (bytes + 255) & ~(size_t)255; return r;
    };
    int*   ec   = (int*)alloc((size_t)N * 4);
    int*   fill = (int*)alloc((size_t)N * 4);
    int*   ptr  = (int*)alloc((size_t)(N + 1) * 4);
    int*   bsum = (int*)alloc((size_t)(NB + 1) * 4);
    int*   csrc = (int*)alloc((size_t)E * 4);
    float* dinv = (float*)alloc((size_t)Mpad * 4);
    float* aggx = (float*)alloc((size_t)N * 3 * 4);
    float* h    = (float*)alloc((size_t)N * 256 * 4);
    unsigned short* hb  = (unsigned short*)alloc((size_t)Mpad * 256 * 2);
    unsigned short* hwc = (unsigned short*)alloc((size_t)Mpad * 256 * 2);  // [8][Mpad][32]
    unsigned short* wt  = (unsigned short*)alloc((size_t)3 * 65536 * 2);
    float* pooled = (float*)alloc((size_t)B * 256 * 4);

    const int* srcl = eidx;
    const int* dstl = eidx + E;

    init_kernel<<<(N + 255) / 256, 256, 0, stream>>>(ec, fill, N);
    deg_kernel<<<(E + 255) / 256, 256, 0, stream>>>(dstl, ec, E);
    scanA<<<NB, 256, 0, stream>>>(ec, bsum, N);
    scanB<<<1, 64, 0, stream>>>(bsum, NB);
    scanC<<<NB, 256, 0, stream>>>(ec, bsum, ptr, N, NB);
    dinv_kernel<<<(Mpad + 255) / 256, 256, 0, stream>>>(ec, dinv, N, Mpad);
    fill_kernel<<<(E + 255) / 256, 256, 0, stream>>>(srcl, dstl, ptr, fill, csrc, E);
    wt_kernel<<<dim3(256, 3), 256, 0, stream>>>(W1, W2, W3, wt);
    aggx_kernel<<<(N + 255) / 256, 256, 0, stream>>>(x, dinv, ptr, csrc, aggx, N);
    h0_kernel<<<Mpad / 4, 256, 0, stream>>>(aggx, W0, b0, h, hb, N, Mpad);

    const float* biases[3] = { b1, b2, b3 };
    int ngrp = (N + 15) / 16;
    for (int l = 0; l < 3; ++l) {
        gemm_kernel<<<Mpad / 64, 256, 0, stream>>>(hb, wt + (size_t)l * 65536, dinv, hwc, Mpad);
        spmm_kernel<<<ngrp * 8, 256, 0, stream>>>(hwc, ptr, csrc, dinv, biases[l],
                                                  h, hb, N, Mpad, (l < 2) ? 1 : 0);
    }

    pool_kernel<<<B, 256, 0, stream>>>(h, batch, pooled, N);
    head_kernel<<<B, 256, 0, stream>>>(pooled, a,
        afc1_w, afc1_b, afc2_w, afc2_b, afc3_w, afc3_b,
        fc1_w, fc1_b, fc2_w, fc2_b,
        ln1_g, ln1_b, ln2_g, ln2_b, ln4_g, ln4_b, ln5_g, ln5_b,
        (float*)d_out);
}

// Round 4
// 614.184 us; speedup vs baseline: 2.0527x; 1.0765x over previous
//
#include <hip/hip_runtime.h>

#define LN_EPS 1e-5f
#define SCAN_CHUNK 4096

typedef __bf16 bf16x8 __attribute__((ext_vector_type(8)));
typedef float f32x4 __attribute__((ext_vector_type(4)));

__device__ __forceinline__ float b2f(unsigned short s) {
    union { unsigned u; float f; } c; c.u = ((unsigned)s) << 16; return c.f;
}
__device__ __forceinline__ float blo(unsigned v) {
    union { unsigned u; float f; } c; c.u = v << 16; return c.f;
}
__device__ __forceinline__ float bhi(unsigned v) {
    union { unsigned u; float f; } c; c.u = v & 0xffff0000u; return c.f;
}
__device__ __forceinline__ unsigned short f2b(float f) {
    union { float f; unsigned u; } c; c.f = f;
    unsigned r = (c.u + 0x7FFFu + ((c.u >> 16) & 1u)) >> 16;
    return (unsigned short)r;
}
__device__ __forceinline__ float leaky(float x) { return x >= 0.f ? x : 0.01f * x; }

// ---------------- CSR build ----------------

__global__ void init_kernel(int* ec, int* fill, int n) {
    int i = blockIdx.x * 256 + threadIdx.x;
    if (i < n) { ec[i] = 0; fill[i] = 0; }
}

__global__ void deg_kernel(const int* __restrict__ dst, int* ec, int e) {
    int i = blockIdx.x * 256 + threadIdx.x;
    if (i < e) atomicAdd(&ec[dst[i]], 1);
}

__global__ void scanA(const int* __restrict__ ec, int* __restrict__ bsum, int n) {
    __shared__ int red[4];
    int b = blockIdx.x, t = threadIdx.x;
    int base = b * SCAN_CHUNK + t * 16;
    int s = 0;
    #pragma unroll
    for (int k = 0; k < 16; ++k) { int i = base + k; if (i < n) s += ec[i]; }
    #pragma unroll
    for (int off = 32; off; off >>= 1) s += __shfl_down(s, off, 64);
    if ((t & 63) == 0) red[t >> 6] = s;
    __syncthreads();
    if (t == 0) bsum[b] = red[0] + red[1] + red[2] + red[3];
}

__global__ void scanB(int* bsum, int nb) {
    if (threadIdx.x == 0) {
        int acc = 0;
        for (int i = 0; i < nb; ++i) { int v = bsum[i]; bsum[i] = acc; acc += v; }
        bsum[nb] = acc;
    }
}

__global__ void scanC(const int* __restrict__ ec, const int* __restrict__ bsum,
                      int* __restrict__ ptr, int n, int nb) {
    __shared__ int wsum[4];
    int b = blockIdx.x, t = threadIdx.x, lane = t & 63, w = t >> 6;
    int base = b * SCAN_CHUNK + t * 16;
    int loc[16]; int s = 0;
    #pragma unroll
    for (int k = 0; k < 16; ++k) { int i = base + k; int v = (i < n) ? ec[i] : 0; loc[k] = s; s += v; }
    int x = s;
    #pragma unroll
    for (int off = 1; off < 64; off <<= 1) { int y = __shfl_up(x, off, 64); if (lane >= off) x += y; }
    if (lane == 63) wsum[w] = x;
    __syncthreads();
    int wexcl = 0;
    #pragma unroll
    for (int ww = 0; ww < 4; ++ww) if (ww < w) wexcl += wsum[ww];
    int toff = bsum[b] + wexcl + (x - s);
    #pragma unroll
    for (int k = 0; k < 16; ++k) { int i = base + k; if (i < n) ptr[i] = toff + loc[k]; }
    if (b == nb - 1 && t == 255) ptr[n] = bsum[nb];
}

__global__ void dinv_kernel(const int* __restrict__ ec, float* __restrict__ dinv, int n, int mpad) {
    int i = blockIdx.x * 256 + threadIdx.x;
    if (i < mpad) dinv[i] = (i < n) ? rsqrtf((float)(ec[i] + 1)) : 0.f;
}

__global__ void fill_kernel(const int* __restrict__ src, const int* __restrict__ dst,
                            const int* __restrict__ ptr, int* fill,
                            int* __restrict__ csrc, int e) {
    int i = blockIdx.x * 256 + threadIdx.x;
    if (i < e) {
        int d = dst[i];
        int pos = atomicAdd(&fill[d], 1);
        csrc[ptr[d] + pos] = src[i];
    }
}

// ---------------- weights: W^T in bf16 ----------------

__global__ void wt_kernel(const float* __restrict__ W1, const float* __restrict__ W2,
                          const float* __restrict__ W3, unsigned short* __restrict__ wt) {
    int k = blockIdx.x, l = blockIdx.y, nn = threadIdx.x;
    const float* W = (l == 0) ? W1 : (l == 1) ? W2 : W3;
    wt[l * 65536 + nn * 256 + k] = f2b(W[k * 256 + nn]);
}

// ---------------- layer 0: aggregate x (3 feats) then tiny matmul ----------------

__global__ void aggx_kernel(const float* __restrict__ x, const float* __restrict__ dinv,
                            const int* __restrict__ ptr, const int* __restrict__ csrc,
                            float* __restrict__ aggx, int n) {
    int i = blockIdx.x * 256 + threadIdx.x;
    if (i >= n) return;
    float di = dinv[i];
    float a0 = di * x[i * 3], a1 = di * x[i * 3 + 1], a2 = di * x[i * 3 + 2];
    float p0 = 0.f, p1 = 0.f, p2 = 0.f;
    float q0 = 0.f, q1 = 0.f, q2 = 0.f;
    float r0 = 0.f, r1 = 0.f, r2 = 0.f;
    int e0 = ptr[i], e1 = ptr[i + 1];
    int e = e0;
    for (; e + 4 <= e1; e += 4) {
        int s0 = csrc[e], s1 = csrc[e + 1], s2 = csrc[e + 2], s3 = csrc[e + 3];
        float d0 = dinv[s0], d1 = dinv[s1], d2 = dinv[s2], d3 = dinv[s3];
        a0 += d0 * x[s0 * 3]; a1 += d0 * x[s0 * 3 + 1]; a2 += d0 * x[s0 * 3 + 2];
        p0 += d1 * x[s1 * 3]; p1 += d1 * x[s1 * 3 + 1]; p2 += d1 * x[s1 * 3 + 2];
        q0 += d2 * x[s2 * 3]; q1 += d2 * x[s2 * 3 + 1]; q2 += d2 * x[s2 * 3 + 2];
        r0 += d3 * x[s3 * 3]; r1 += d3 * x[s3 * 3 + 1]; r2 += d3 * x[s3 * 3 + 2];
    }
    for (; e < e1; ++e) {
        int s = csrc[e]; float ds = dinv[s];
        a0 += ds * x[s * 3]; a1 += ds * x[s * 3 + 1]; a2 += ds * x[s * 3 + 2];
    }
    a0 += (p0 + q0) + r0; a1 += (p1 + q1) + r1; a2 += (p2 + q2) + r2;
    aggx[i * 3] = a0 * di; aggx[i * 3 + 1] = a1 * di; aggx[i * 3 + 2] = a2 * di;
}

// h0 = aggx @ W0 + b0; write h (f32, row-major) and hbs = bf16(dinv*h) chunked [8][mpad][32]
__global__ __launch_bounds__(256) void h0_kernel(const float* __restrict__ aggx,
                          const float* __restrict__ W0, const float* __restrict__ b0,
                          const float* __restrict__ dinv,
                          float* __restrict__ h, unsigned short* __restrict__ hbs,
                          int n, int mpad) {
    int t = threadIdx.x;
    int row = blockIdx.x * 4 + (t >> 6);
    int f = (t & 63) * 4;
    if (row >= n) return;
    float a0 = aggx[row * 3], a1 = aggx[row * 3 + 1], a2 = aggx[row * 3 + 2];
    float4 w0 = *(const float4*)(W0 + f);
    float4 w1 = *(const float4*)(W0 + 256 + f);
    float4 w2 = *(const float4*)(W0 + 512 + f);
    float4 bb = *(const float4*)(b0 + f);
    float4 v;
    v.x = bb.x + a0 * w0.x + a1 * w1.x + a2 * w2.x;
    v.y = bb.y + a0 * w0.y + a1 * w1.y + a2 * w2.y;
    v.z = bb.z + a0 * w0.z + a1 * w1.z + a2 * w2.z;
    v.w = bb.w + a0 * w0.w + a1 * w1.w + a2 * w2.w;
    *(float4*)(h + (size_t)row * 256 + f) = v;
    float di = dinv[row];
    ushort4 o;
    o.x = f2b(di * v.x); o.y = f2b(di * v.y); o.z = f2b(di * v.z); o.w = f2b(di * v.w);
    *(ushort4*)(hbs + ((size_t)(f >> 5) * mpad + row) * 32 + (f & 31)) = o;
}

// ---------------- SpMM pure gather: agg[c][d][*] = dinv[d] * (hbs[c][d] + sum_src hbs[c][src]) ----------------

__global__ __launch_bounds__(256) void spmm_kernel(
    const unsigned short* __restrict__ hbs,
    const int* __restrict__ ptr, const int* __restrict__ csrc,
    const float* __restrict__ dinv,
    unsigned short* __restrict__ agg,
    int n, int mpad) {
    int chunk = blockIdx.x & 7;   // chunk pinned to XCD (round-robin dispatch)
    int g = blockIdx.x >> 3;
    int t = threadIdx.x;
    int node = g * 16 + (t >> 4);
    if (node >= n) return;
    int fl = t & 15;
    const char* cb = (const char*)(hbs + (size_t)chunk * mpad * 32);
    unsigned loff = (unsigned)(fl << 2);
    int e0 = ptr[node], e1 = ptr[node + 1];
    unsigned sv = *(const unsigned*)(cb + (((unsigned)node << 6) | loff));
    float a0 = blo(sv), a1 = bhi(sv);
    float p0 = 0.f, p1 = 0.f, q0 = 0.f, q1 = 0.f, r0 = 0.f, r1 = 0.f, s0 = 0.f, s1 = 0.f;
    int len = e1 - e0;
    int nblk = (len + 7) >> 3;
    int e1m = e1 - 1;
    int idx[8];
    if (nblk > 0) {
        #pragma unroll
        for (int j = 0; j < 8; ++j) idx[j] = csrc[min(e0 + j, e1m)];
    }
    int e = e0;
    for (int b = 0; b < nblk; ++b) {
        int nidx[8];
        bool more = (b + 1 < nblk);
        int en = e + 8;
        #pragma unroll
        for (int j = 0; j < 8; ++j) if (more) nidx[j] = csrc[min(en + j, e1m)];
        unsigned u[8];
        #pragma unroll
        for (int j = 0; j < 8; ++j) u[j] = *(const unsigned*)(cb + (((unsigned)idx[j] << 6) | loff));
        #pragma unroll
        for (int j = 0; j < 8; ++j) if (e + j >= e1) u[j] = 0u;
        a0 += blo(u[0]); a1 += bhi(u[0]);
        p0 += blo(u[1]); p1 += bhi(u[1]);
        q0 += blo(u[2]); q1 += bhi(u[2]);
        r0 += blo(u[3]); r1 += bhi(u[3]);
        s0 += blo(u[4]); s1 += bhi(u[4]);
        a0 += blo(u[5]); a1 += bhi(u[5]);
        p0 += blo(u[6]); p1 += bhi(u[6]);
        q0 += blo(u[7]); q1 += bhi(u[7]);
        #pragma unroll
        for (int j = 0; j < 8; ++j) idx[j] = nidx[j];
        e = en;
    }
    a0 += (p0 + q0) + (r0 + s0);
    a1 += (p1 + q1) + (r1 + s1);
    float di = dinv[node];
    unsigned ob = ((unsigned)f2b(di * a1) << 16) | (unsigned)f2b(di * a0);
    *(unsigned*)((char*)agg + (size_t)chunk * mpad * 64 + (((unsigned)node << 6) | loff)) = ob;
}

// ---------------- GEMM + fused epilogue: h += leaky(agg@W + bias); hbs = bf16(dinv*h) ----------------

__global__ __launch_bounds__(256) void gemm_kernel(const unsigned short* __restrict__ A,   // agg chunked
                                                   const unsigned short* __restrict__ Bt,  // Wt row-major [256][256]
                                                   const float* __restrict__ bias,
                                                   const float* __restrict__ dinv,
                                                   float* __restrict__ h,
                                                   unsigned short* __restrict__ hbs,
                                                   int mpad, int write_hbs) {
    const int K = 256;
    int wid = threadIdx.x >> 6, lane = threadIdx.x & 63;
    int m0 = blockIdx.x * 64;
    int n0 = wid * 64;
    int lr = lane & 15, lg = lane >> 4;
    f32x4 acc[4][4];
    #pragma unroll
    for (int i = 0; i < 4; i++)
        #pragma unroll
        for (int j = 0; j < 4; j++) acc[i][j] = (f32x4)(0.f);
    // A chunked: element offset ((kk/32)*mpad + row)*32 + lg*8, row = m0+lr+mi*16
    const unsigned short* Ap = A + ((size_t)(m0 + lr)) * 32 + lg * 8;
    const unsigned short* Bp = Bt + (size_t)(n0 + lr) * K + lg * 8;
    #pragma unroll
    for (int kc = 0; kc < 8; ++kc) {
        bf16x8 af[4], bfr[4];
        #pragma unroll
        for (int mi = 0; mi < 4; mi++)
            af[mi] = *(const bf16x8*)(Ap + (size_t)kc * mpad * 32 + mi * 512);
        #pragma unroll
        for (int ni = 0; ni < 4; ni++)
            bfr[ni] = *(const bf16x8*)(Bp + (size_t)ni * 16 * K + kc * 32);
        #pragma unroll
        for (int mi = 0; mi < 4; mi++)
            #pragma unroll
            for (int ni = 0; ni < 4; ni++)
                acc[mi][ni] = __builtin_amdgcn_mfma_f32_16x16x32_bf16(af[mi], bfr[ni], acc[mi][ni], 0, 0, 0);
    }
    #pragma unroll
    for (int mi = 0; mi < 4; mi++) {
        int r0 = m0 + mi * 16 + lg * 4;
        float4 dv = *(const float4*)(dinv + r0);
        #pragma unroll
        for (int ni = 0; ni < 4; ni++) {
            int c = n0 + ni * 16 + lr;
            float bv = bias[c];
            int ch = c >> 5, cf = c & 31;
            float vr[4];
            #pragma unroll
            for (int j = 0; j < 4; ++j) {
                size_t ho = (size_t)(r0 + j) * 256 + c;
                float v = leaky(acc[mi][ni][j] + bv) + h[ho];
                h[ho] = v;
                vr[j] = v;
            }
            if (write_hbs) {
                unsigned short* hp = hbs + ((size_t)ch * mpad + r0) * 32 + cf;
                hp[0]  = f2b(vr[0] * dv.x);
                hp[32] = f2b(vr[1] * dv.y);
                hp[64] = f2b(vr[2] * dv.z);
                hp[96] = f2b(vr[3] * dv.w);
            }
        }
    }
}

// ---------------- segment max pooling ----------------

__global__ __launch_bounds__(256) void pool_kernel(const float* __restrict__ h,
                                                   const int* __restrict__ batch,
                                                   float* __restrict__ pooled, int n) {
    int b = blockIdx.x, d = threadIdx.x;
    int lo = 0, hi = n;
    while (lo < hi) { int m = (lo + hi) >> 1; if (batch[m] < b) lo = m + 1; else hi = m; }
    int s = lo;
    lo = 0; hi = n;
    while (lo < hi) { int m = (lo + hi) >> 1; if (batch[m] < b + 1) lo = m + 1; else hi = m; }
    int e = lo;
    float mx = -3.402823466e38f;
    for (int r = s; r < e; ++r) mx = fmaxf(mx, h[(size_t)r * 256 + d]);
    pooled[(size_t)b * 256 + d] = mx;
}

// ---------------- head ----------------

__device__ __forceinline__ float blk_sum(float v, float* red) {
    #pragma unroll
    for (int off = 32; off; off >>= 1) v += __shfl_down(v, off, 64);
    int lane = threadIdx.x & 63, wid = threadIdx.x >> 6;
    if (lane == 0) red[wid] = v;
    __syncthreads();
    float s = red[0] + red[1] + red[2] + red[3];
    __syncthreads();
    return s;
}

__global__ __launch_bounds__(256) void head_kernel(
    const float* __restrict__ pooled, const float* __restrict__ a,
    const float* __restrict__ afc1_w, const float* __restrict__ afc1_b,
    const float* __restrict__ afc2_w, const float* __restrict__ afc2_b,
    const float* __restrict__ afc3_w, const float* __restrict__ afc3_b,
    const float* __restrict__ fc1_w, const float* __restrict__ fc1_b,
    const float* __restrict__ fc2_w, const float* __restrict__ fc2_b,
    const float* __restrict__ ln1_g, const float* __restrict__ ln1_b,
    const float* __restrict__ ln2_g, const float* __restrict__ ln2_b,
    const float* __restrict__ ln4_g, const float* __restrict__ ln4_b,
    const float* __restrict__ ln5_g, const float* __restrict__ ln5_b,
    float* __restrict__ out) {
    __shared__ float red[4];
    __shared__ float sM[2];
    __shared__ float s1[56], s2[56], sZ[256], sT[64];
    int b = blockIdx.x, tid = threadIdx.x;

    float pv = pooled[(size_t)b * 256 + tid];
    float m = blk_sum(pv, red) * (1.f / 256.f);
    float d0 = pv - m;
    float var = blk_sum(d0 * d0, red) * (1.f / 256.f);
    float V = d0 * rsqrtf(var + LN_EPS) * ln2_g[tid] + ln2_b[tid];

    if (tid < 56) {
        float acc = afc1_b[tid];
        #pragma unroll
        for (int k = 0; k < 7; ++k) acc += a[b * 7 + k] * afc1_w[k * 56 + tid];
        s1[tid] = leaky(acc);
    }
    __syncthreads();
    if (tid == 0) {
        float s = 0.f; for (int k = 0; k < 56; ++k) s += s1[k];
        float mm = s / 56.f;
        float q = 0.f; for (int k = 0; k < 56; ++k) { float d = s1[k] - mm; q += d * d; }
        sM[0] = mm; sM[1] = rsqrtf(q / 56.f + LN_EPS);
    }
    __syncthreads();
    if (tid < 56) s1[tid] = (s1[tid] - sM[0]) * sM[1] * ln5_g[tid] + ln5_b[tid];
    __syncthreads();
    if (tid < 56) {
        float acc = afc2_b[tid];
        for (int k = 0; k < 56; ++k) acc += s1[k] * afc2_w[k * 56 + tid];
        s2[tid] = leaky(acc);
    }
    __syncthreads();
    float acc = afc3_b[tid];
    for (int k = 0; k < 56; ++k) acc += s2[k] * afc3_w[k * 256 + tid];
    acc = leaky(acc);
    m = blk_sum(acc, red) * (1.f / 256.f);
    d0 = acc - m;
    var = blk_sum(d0 * d0, red) * (1.f / 256.f);
    float av = d0 * rsqrtf(var + LN_EPS) * ln1_g[tid] + ln1_b[tid];

    float z = V * av;
    sZ[tid] = z;
    __syncthreads();
    if (tid < 64) {
        float a2 = fc1_b[tid];
        for (int k = 0; k < 256; ++k) a2 += sZ[k] * fc1_w[k * 64 + tid];
        sT[tid] = leaky(a2);
    }
    __syncthreads();
    if (tid == 0) {
        float s = 0.f; for (int k = 0; k < 64; ++k) s += sT[k];
        float mm = s / 64.f;
        float q = 0.f; for (int k = 0; k < 64; ++k) { float d = sT[k] - mm; q += d * d; }
        float r = rsqrtf(q / 64.f + LN_EPS);
        float o = fc2_b[0];
        for (int k = 0; k < 64; ++k) {
            float zz = (sT[k] - mm) * r * ln4_g[k] + ln4_b[k];
            o += zz * fc2_w[k];
        }
        out[b] = o;
    }
}

// ---------------- launch ----------------

extern "C" void kernel_launch(void* const* d_in, const int* in_sizes, int n_in,
                              void* d_out, int out_size, void* d_ws, size_t ws_size,
                              hipStream_t stream) {
    const float* x     = (const float*)d_in[0];
    const int*   eidx  = (const int*)d_in[1];
    const int*   batch = (const int*)d_in[2];
    const float* a     = (const float*)d_in[3];
    const float* W0 = (const float*)d_in[4];  const float* b0 = (const float*)d_in[5];
    const float* W1 = (const float*)d_in[6];  const float* b1 = (const float*)d_in[7];
    const float* W2 = (const float*)d_in[8];  const float* b2 = (const float*)d_in[9];
    const float* W3 = (const float*)d_in[10]; const float* b3 = (const float*)d_in[11];
    const float* afc1_w = (const float*)d_in[12]; const float* afc1_b = (const float*)d_in[13];
    const float* afc2_w = (const float*)d_in[14]; const float* afc2_b = (const float*)d_in[15];
    const float* afc3_w = (const float*)d_in[16]; const float* afc3_b = (const float*)d_in[17];
    const float* fc1_w  = (const float*)d_in[18]; const float* fc1_b  = (const float*)d_in[19];
    const float* fc2_w  = (const float*)d_in[20]; const float* fc2_b  = (const float*)d_in[21];
    const float* ln1_g = (const float*)d_in[22]; const float* ln1_b = (const float*)d_in[23];
    const float* ln2_g = (const float*)d_in[24]; const float* ln2_b = (const float*)d_in[25];
    const float* ln4_g = (const float*)d_in[26]; const float* ln4_b = (const float*)d_in[27];
    const float* ln5_g = (const float*)d_in[28]; const float* ln5_b = (const float*)d_in[29];

    int N = in_sizes[0] / 3;
    int E = in_sizes[1] / 2;
    int B = in_sizes[3] / 7;
    int Mpad = ((N + 63) / 64) * 64;
    int NB = (N + SCAN_CHUNK - 1) / SCAN_CHUNK;

    char* p = (char*)d_ws;
    auto alloc = [&](size_t bytes) -> char* {
        char* r = p; p += (bytes + 255) & ~(size_t)255; return r;
    };
    int*   ec   = (int*)alloc((size_t)N * 4);
    int*   fill = (int*)alloc((size_t)N * 4);
    int*   ptr  = (int*)alloc((size_t)(N + 1) * 4);
    int*   bsum = (int*)alloc((size_t)(NB + 1) * 4);
    int*   csrc = (int*)alloc((size_t)E * 4);
    float* dinv = (float*)alloc((size_t)Mpad * 4);
    float* aggx = (float*)alloc((size_t)N * 3 * 4);
    float* h    = (float*)alloc((size_t)Mpad * 256 * 4);
    unsigned short* hbs = (unsigned short*)alloc((size_t)Mpad * 256 * 2);  // [8][Mpad][32]
    unsigned short* agg = (unsigned short*)alloc((size_t)Mpad * 256 * 2);  // [8][Mpad][32]
    unsigned short* wt  = (unsigned short*)alloc((size_t)3 * 65536 * 2);
    float* pooled = (float*)alloc((size_t)B * 256 * 4);

    const int* srcl = eidx;
    const int* dstl = eidx + E;

    init_kernel<<<(N + 255) / 256, 256, 0, stream>>>(ec, fill, N);
    deg_kernel<<<(E + 255) / 256, 256, 0, stream>>>(dstl, ec, E);
    scanA<<<NB, 256, 0, stream>>>(ec, bsum, N);
    scanB<<<1, 64, 0, stream>>>(bsum, NB);
    scanC<<<NB, 256, 0, stream>>>(ec, bsum, ptr, N, NB);
    dinv_kernel<<<(Mpad + 255) / 256, 256, 0, stream>>>(ec, dinv, N, Mpad);
    fill_kernel<<<(E + 255) / 256, 256, 0, stream>>>(srcl, dstl, ptr, fill, csrc, E);
    wt_kernel<<<dim3(256, 3), 256, 0, stream>>>(W1, W2, W3, wt);
    aggx_kernel<<<(N + 255) / 256, 256, 0, stream>>>(x, dinv, ptr, csrc, aggx, N);
    h0_kernel<<<(N + 3) / 4, 256, 0, stream>>>(aggx, W0, b0, dinv, h, hbs, N, Mpad);

    const float* biases[3] = { b1, b2, b3 };
    int ngrp = (N + 15) / 16;
    for (int l = 0; l < 3; ++l) {
        spmm_kernel<<<ngrp * 8, 256, 0, stream>>>(hbs, ptr, csrc, dinv, agg, N, Mpad);
        gemm_kernel<<<Mpad / 64, 256, 0, stream>>>(agg, wt + (size_t)l * 65536, biases[l],
                                                   dinv, h, hbs, Mpad, (l < 2) ? 1 : 0);
    }

    pool_kernel<<<B, 256, 0, stream>>>(h, batch, pooled, N);
    head_kernel<<<B, 256, 0, stream>>>(pooled, a,
        afc1_w, afc1_b, afc2_w, afc2_b, afc3_w, afc3_b,
        fc1_w, fc1_b, fc2_w, fc2_b,
        ln1_g, ln1_b, ln2_g, ln2_b, ln4_g, ln4_b, ln5_g, ln5_b,
        (float*)d_out);
}

// Round 7
// 561.258 us; speedup vs baseline: 2.2463x; 1.0943x over previous
//
#include <hip/hip_runtime.h>

#define LN_EPS 1e-5f
#define SCAN_CHUNK 4096

typedef __bf16 bf16x8 __attribute__((ext_vector_type(8)));
typedef float f32x4 __attribute__((ext_vector_type(4)));
typedef float f32x2 __attribute__((ext_vector_type(2)));

__device__ __forceinline__ float b2f(unsigned short s) {
    union { unsigned u; float f; } c; c.u = ((unsigned)s) << 16; return c.f;
}
__device__ __forceinline__ unsigned short f2b(float f) {
    union { float f; unsigned u; } c; c.f = f;
    unsigned r = (c.u + 0x7FFFu + ((c.u >> 16) & 1u)) >> 16;
    return (unsigned short)r;
}
__device__ __forceinline__ f32x2 up2(unsigned u) {
    union { unsigned u; float f; } lo, hi;
    lo.u = u << 16; hi.u = u & 0xffff0000u;
    f32x2 r; r.x = lo.f; r.y = hi.f; return r;
}
__device__ __forceinline__ unsigned pk2(f32x2 v) {
    return ((unsigned)f2b(v.y) << 16) | (unsigned)f2b(v.x);
}
__device__ __forceinline__ float leaky(float x) { return x >= 0.f ? x : 0.01f * x; }
__device__ __forceinline__ unsigned encf(float f) {
    union { float f; unsigned u; } c; c.f = f;
    return ((int)c.u < 0) ? ~c.u : (c.u | 0x80000000u);
}
__device__ __forceinline__ float decf(unsigned u) {
    union { unsigned u; float f; } c;
    c.u = (u & 0x80000000u) ? (u & 0x7FFFFFFFu) : ~u;
    return c.f;
}

// ---------------- CSR build (padded-to-8 edge lists) ----------------

__global__ void init_kernel(int* ec, int* fill, int n) {
    int i = blockIdx.x * 256 + threadIdx.x;
    if (i < n) { ec[i] = 0; fill[i] = 0; }
}

__global__ void deg_kernel(const int* __restrict__ dst, int* ec, int e) {
    int i = blockIdx.x * 256 + threadIdx.x;
    if (i < e) atomicAdd(&ec[dst[i]], 1);
}

__global__ void scanA(const int* __restrict__ ec, int* __restrict__ bsum, int n) {
    __shared__ int red[4];
    int b = blockIdx.x, t = threadIdx.x;
    int base = b * SCAN_CHUNK + t * 16;
    int s = 0;
    #pragma unroll
    for (int k = 0; k < 16; ++k) { int i = base + k; if (i < n) s += (ec[i] + 7) & ~7; }
    #pragma unroll
    for (int off = 32; off; off >>= 1) s += __shfl_down(s, off, 64);
    if ((t & 63) == 0) red[t >> 6] = s;
    __syncthreads();
    if (t == 0) bsum[b] = red[0] + red[1] + red[2] + red[3];
}

__global__ void scanB(int* bsum, int nb) {
    if (threadIdx.x == 0) {
        int acc = 0;
        for (int i = 0; i < nb; ++i) { int v = bsum[i]; bsum[i] = acc; acc += v; }
        bsum[nb] = acc;
    }
}

__global__ void scanC(const int* __restrict__ ec, const int* __restrict__ bsum,
                      int* __restrict__ ptr, int n, int nb) {
    __shared__ int wsum[4];
    int b = blockIdx.x, t = threadIdx.x, lane = t & 63, w = t >> 6;
    int base = b * SCAN_CHUNK + t * 16;
    int loc[16]; int s = 0;
    #pragma unroll
    for (int k = 0; k < 16; ++k) {
        int i = base + k; int v = (i < n) ? ((ec[i] + 7) & ~7) : 0;
        loc[k] = s; s += v;
    }
    int x = s;
    #pragma unroll
    for (int off = 1; off < 64; off <<= 1) { int y = __shfl_up(x, off, 64); if (lane >= off) x += y; }
    if (lane == 63) wsum[w] = x;
    __syncthreads();
    int wexcl = 0;
    #pragma unroll
    for (int ww = 0; ww < 4; ++ww) if (ww < w) wexcl += wsum[ww];
    int toff = bsum[b] + wexcl + (x - s);
    #pragma unroll
    for (int k = 0; k < 16; ++k) { int i = base + k; if (i < n) ptr[i] = toff + loc[k]; }
    if (b == nb - 1 && t == 255) ptr[n] = bsum[nb];
}

__global__ void dinv_kernel(const int* __restrict__ ec, float* __restrict__ dinv, int n, int mpad) {
    int i = blockIdx.x * 256 + threadIdx.x;
    if (i < mpad) dinv[i] = (i < n) ? rsqrtf((float)(ec[i] + 1)) : 0.f;
}

// xp[i] = {dinv*x0, dinv*x1, dinv*x2, 0}; zero rows for i >= n
__global__ void xp_kernel(const float* __restrict__ x, const float* __restrict__ dinv,
                          float4* __restrict__ xp, int n, int mpad) {
    int i = blockIdx.x * 256 + threadIdx.x;
    if (i >= mpad) return;
    float4 v = make_float4(0.f, 0.f, 0.f, 0.f);
    if (i < n) {
        float d = dinv[i];
        v.x = d * x[i * 3]; v.y = d * x[i * 3 + 1]; v.z = d * x[i * 3 + 2];
    }
    xp[i] = v;
}

// fill all padded slots with zero-row offset (n<<6); fill_kernel overwrites real slots
__global__ void csrc_init_kernel(const int* __restrict__ ptr, int* __restrict__ csrc, int n) {
    int i = blockIdx.x * 256 + threadIdx.x;
    if (i < ptr[n]) csrc[i] = n << 6;
}

__global__ void fill_kernel(const int* __restrict__ src, const int* __restrict__ dst,
                            const int* __restrict__ ptr, int* fill,
                            int* __restrict__ csrc, int e) {
    int i = blockIdx.x * 256 + threadIdx.x;
    if (i < e) {
        int d = dst[i];
        int pos = atomicAdd(&fill[d], 1);
        csrc[ptr[d] + pos] = src[i] << 6;   // pre-shifted byte offset (64B rows)
    }
}

// ---------------- weights: W^T in bf16 ----------------

__global__ void wt_kernel(const float* __restrict__ W1, const float* __restrict__ W2,
                          const float* __restrict__ W3, unsigned short* __restrict__ wt) {
    int k = blockIdx.x, l = blockIdx.y, nn = threadIdx.x;
    const float* W = (l == 0) ? W1 : (l == 1) ? W2 : W3;
    wt[l * 65536 + nn * 256 + k] = f2b(W[k * 256 + nn]);
}

// ---------------- layer 0 ----------------

__global__ void aggx_kernel(const float4* __restrict__ xp, const float* __restrict__ dinv,
                            const int* __restrict__ ptr, const int* __restrict__ csrc,
                            float* __restrict__ aggx, int n) {
    int i = blockIdx.x * 256 + threadIdx.x;
    if (i >= n) return;
    const char* xb = (const char*)xp;
    float4 self = xp[i];
    float a0 = self.x, a1 = self.y, a2 = self.z;
    float p0 = 0.f, p1 = 0.f, p2 = 0.f;
    float q0 = 0.f, q1 = 0.f, q2 = 0.f;
    float r0 = 0.f, r1 = 0.f, r2 = 0.f;
    int e0 = ptr[i], e1 = ptr[i + 1];
    for (int e = e0; e < e1; e += 4) {
        int4 v = *(const int4*)(csrc + e);
        float4 u0 = *(const float4*)(xb + (((unsigned)v.x) >> 2));
        float4 u1 = *(const float4*)(xb + (((unsigned)v.y) >> 2));
        float4 u2 = *(const float4*)(xb + (((unsigned)v.z) >> 2));
        float4 u3 = *(const float4*)(xb + (((unsigned)v.w) >> 2));
        a0 += u0.x; a1 += u0.y; a2 += u0.z;
        p0 += u1.x; p1 += u1.y; p2 += u1.z;
        q0 += u2.x; q1 += u2.y; q2 += u2.z;
        r0 += u3.x; r1 += u3.y; r2 += u3.z;
    }
    a0 += (p0 + q0) + r0; a1 += (p1 + q1) + r1; a2 += (p2 + q2) + r2;
    float di = dinv[i];
    aggx[i * 3] = a0 * di; aggx[i * 3 + 1] = a1 * di; aggx[i * 3 + 2] = a2 * di;
}

// h0 = aggx @ W0 + b0; h (f32) rows<n; hbs = bf16(dinv*h) chunked [8][mpad][32], zero pad rows
__global__ __launch_bounds__(256) void h0_kernel(const float* __restrict__ aggx,
                          const float* __restrict__ W0, const float* __restrict__ b0,
                          const float* __restrict__ dinv,
                          float* __restrict__ h, unsigned short* __restrict__ hbs,
                          int n, int mpad) {
    int t = threadIdx.x;
    int row = blockIdx.x * 4 + (t >> 6);
    int f = (t & 63) * 4;
    if (row >= mpad) return;
    unsigned short* hp = hbs + ((size_t)(f >> 5) * mpad + row) * 32 + (f & 31);
    if (row < n) {
        float a0 = aggx[row * 3], a1 = aggx[row * 3 + 1], a2 = aggx[row * 3 + 2];
        float4 w0 = *(const float4*)(W0 + f);
        float4 w1 = *(const float4*)(W0 + 256 + f);
        float4 w2 = *(const float4*)(W0 + 512 + f);
        float4 bb = *(const float4*)(b0 + f);
        float4 v;
        v.x = bb.x + a0 * w0.x + a1 * w1.x + a2 * w2.x;
        v.y = bb.y + a0 * w0.y + a1 * w1.y + a2 * w2.y;
        v.z = bb.z + a0 * w0.z + a1 * w1.z + a2 * w2.z;
        v.w = bb.w + a0 * w0.w + a1 * w1.w + a2 * w2.w;
        *(float4*)(h + (size_t)row * 256 + f) = v;
        float di = dinv[row];
        ushort4 o;
        o.x = f2b(di * v.x); o.y = f2b(di * v.y); o.z = f2b(di * v.z); o.w = f2b(di * v.w);
        *(ushort4*)hp = o;
    } else {
        ushort4 o; o.x = 0; o.y = 0; o.z = 0; o.w = 0;
        *(ushort4*)hp = o;
    }
}

// ---------------- SpMM pure gather, padded lists, dwordx4 payloads ----------------

__global__ __launch_bounds__(256) void spmm_kernel(
    const unsigned short* __restrict__ hbs,
    const int* __restrict__ ptr, const int* __restrict__ csrc,
    const float* __restrict__ dinv,
    unsigned short* __restrict__ agg,
    int n, int mpad) {
    int chunk = blockIdx.x & 7;   // chunk pinned to XCD (round-robin dispatch)
    int g = blockIdx.x >> 3;
    int t = threadIdx.x;
    int node = g * 64 + (t >> 2);
    if (node >= n) return;
    unsigned loff = (unsigned)((t & 3) << 4);
    const char* cb = (const char*)hbs + (size_t)chunk * mpad * 64;
    int e0 = ptr[node], e1 = ptr[node + 1];
    uint4 own = *(const uint4*)(cb + (((unsigned)node << 6) | loff));
    f32x2 accA0 = up2(own.x), accA1 = up2(own.y), accA2 = up2(own.z), accA3 = up2(own.w);
    f32x2 accB0 = (f32x2)(0.f), accB1 = (f32x2)(0.f), accB2 = (f32x2)(0.f), accB3 = (f32x2)(0.f);
    int e = e0;
    int4 ia, ib;
    if (e < e1) { ia = *(const int4*)(csrc + e); ib = *(const int4*)(csrc + e + 4); }
    while (e < e1) {
        int en = e + 8;
        int4 na, nb;
        if (en < e1) { na = *(const int4*)(csrc + en); nb = *(const int4*)(csrc + en + 4); }
        uint4 u0 = *(const uint4*)(cb + ((unsigned)ia.x | loff));
        uint4 u1 = *(const uint4*)(cb + ((unsigned)ia.y | loff));
        uint4 u2 = *(const uint4*)(cb + ((unsigned)ia.z | loff));
        uint4 u3 = *(const uint4*)(cb + ((unsigned)ia.w | loff));
        uint4 u4 = *(const uint4*)(cb + ((unsigned)ib.x | loff));
        uint4 u5 = *(const uint4*)(cb + ((unsigned)ib.y | loff));
        uint4 u6 = *(const uint4*)(cb + ((unsigned)ib.z | loff));
        uint4 u7 = *(const uint4*)(cb + ((unsigned)ib.w | loff));
        accA0 += up2(u0.x); accA1 += up2(u0.y); accA2 += up2(u0.z); accA3 += up2(u0.w);
        accB0 += up2(u1.x); accB1 += up2(u1.y); accB2 += up2(u1.z); accB3 += up2(u1.w);
        accA0 += up2(u2.x); accA1 += up2(u2.y); accA2 += up2(u2.z); accA3 += up2(u2.w);
        accB0 += up2(u3.x); accB1 += up2(u3.y); accB2 += up2(u3.z); accB3 += up2(u3.w);
        accA0 += up2(u4.x); accA1 += up2(u4.y); accA2 += up2(u4.z); accA3 += up2(u4.w);
        accB0 += up2(u5.x); accB1 += up2(u5.y); accB2 += up2(u5.z); accB3 += up2(u5.w);
        accA0 += up2(u6.x); accA1 += up2(u6.y); accA2 += up2(u6.z); accA3 += up2(u6.w);
        accB0 += up2(u7.x); accB1 += up2(u7.y); accB2 += up2(u7.z); accB3 += up2(u7.w);
        ia = na; ib = nb; e = en;
    }
    float di = dinv[node];
    f32x2 dd; dd.x = di; dd.y = di;
    accA0 = (accA0 + accB0) * dd;
    accA1 = (accA1 + accB1) * dd;
    accA2 = (accA2 + accB2) * dd;
    accA3 = (accA3 + accB3) * dd;
    uint4 o;
    o.x = pk2(accA0); o.y = pk2(accA1); o.z = pk2(accA2); o.w = pk2(accA3);
    *(uint4*)((char*)agg + (size_t)chunk * mpad * 64 + (((unsigned)node << 6) | loff)) = o;
}

// ---------------- GEMM + fused epilogue ----------------
// layers 1,2: h += leaky(agg@W + bias); hbs = bf16(dinv*h)
// layer 3 (last): v = leaky(..)+h, atomicMax(pooled) per segment; no stores

__global__ __launch_bounds__(256) void gemm_kernel(const unsigned short* __restrict__ A,
                                                   const unsigned short* __restrict__ Bt,
                                                   const float* __restrict__ bias,
                                                   const float* __restrict__ dinv,
                                                   float* __restrict__ h,
                                                   unsigned short* __restrict__ hbs,
                                                   const int* __restrict__ batch,
                                                   unsigned* __restrict__ pooledu,
                                                   int mpad, int n, int write_hbs, int last) {
    const int K = 256;
    __shared__ int sb[64];
    int wid = threadIdx.x >> 6, lane = threadIdx.x & 63;
    int m0 = blockIdx.x * 64;
    if (last && threadIdx.x < 64) {
        int r = m0 + threadIdx.x;
        sb[threadIdx.x] = (r < n) ? batch[r] : -1;
    }
    __syncthreads();
    int n0 = wid * 64;
    int lr = lane & 15, lg = lane >> 4;
    f32x4 acc[4][4];
    #pragma unroll
    for (int i = 0; i < 4; i++)
        #pragma unroll
        for (int j = 0; j < 4; j++) acc[i][j] = (f32x4)(0.f);
    const unsigned short* Ap = A + ((size_t)(m0 + lr)) * 32 + lg * 8;
    const unsigned short* Bp = Bt + (size_t)(n0 + lr) * K + lg * 8;
    #pragma unroll
    for (int kc = 0; kc < 8; ++kc) {
        bf16x8 af[4], bfr[4];
        #pragma unroll
        for (int mi = 0; mi < 4; mi++)
            af[mi] = *(const bf16x8*)(Ap + (size_t)kc * mpad * 32 + mi * 512);
        #pragma unroll
        for (int ni = 0; ni < 4; ni++)
            bfr[ni] = *(const bf16x8*)(Bp + (size_t)ni * 16 * K + kc * 32);
        #pragma unroll
        for (int mi = 0; mi < 4; mi++)
            #pragma unroll
            for (int ni = 0; ni < 4; ni++)
                acc[mi][ni] = __builtin_amdgcn_mfma_f32_16x16x32_bf16(af[mi], bfr[ni], acc[mi][ni], 0, 0, 0);
    }
    if (!last) {
        #pragma unroll
        for (int mi = 0; mi < 4; mi++) {
            int r0 = m0 + mi * 16 + lg * 4;
            float4 dv = *(const float4*)(dinv + r0);
            #pragma unroll
            for (int ni = 0; ni < 4; ni++) {
                int c = n0 + ni * 16 + lr;
                float bv = bias[c];
                int ch = c >> 5, cf = c & 31;
                float vr[4];
                #pragma unroll
                for (int j = 0; j < 4; ++j) {
                    size_t ho = (size_t)(r0 + j) * 256 + c;
                    float v = leaky(acc[mi][ni][j] + bv) + h[ho];
                    h[ho] = v;
                    vr[j] = v;
                }
                if (write_hbs) {
                    unsigned short* hp = hbs + ((size_t)ch * mpad + r0) * 32 + cf;
                    hp[0]  = f2b(vr[0] * dv.x);
                    hp[32] = f2b(vr[1] * dv.y);
                    hp[64] = f2b(vr[2] * dv.z);
                    hp[96] = f2b(vr[3] * dv.w);
                }
            }
        }
    } else {
        #pragma unroll
        for (int ni = 0; ni < 4; ni++) {
            int c = n0 + ni * 16 + lr;
            float bv = bias[c];
            int cs = -1; float cm = 0.f;
            #pragma unroll
            for (int mi = 0; mi < 4; mi++) {
                int rb = mi * 16 + lg * 4;
                #pragma unroll
                for (int j = 0; j < 4; ++j) {
                    int seg = sb[rb + j];
                    float v = leaky(acc[mi][ni][j] + bv) + h[(size_t)(m0 + rb + j) * 256 + c];
                    if (seg >= 0) {
                        if (seg != cs) {
                            if (cs >= 0) atomicMax(pooledu + (size_t)cs * 256 + c, encf(cm));
                            cs = seg; cm = v;
                        } else {
                            cm = fmaxf(cm, v);
                        }
                    }
                }
            }
            if (cs >= 0) atomicMax(pooledu + (size_t)cs * 256 + c, encf(cm));
        }
    }
}

__global__ void pool_init_kernel(unsigned* pooledu) {
    pooledu[blockIdx.x * 256 + threadIdx.x] = 0u;
}

// ---------------- head ----------------

__device__ __forceinline__ float blk_sum(float v, float* red) {
    #pragma unroll
    for (int off = 32; off; off >>= 1) v += __shfl_down(v, off, 64);
    int lane = threadIdx.x & 63, wid = threadIdx.x >> 6;
    if (lane == 0) red[wid] = v;
    __syncthreads();
    float s = red[0] + red[1] + red[2] + red[3];
    __syncthreads();
    return s;
}

__global__ __launch_bounds__(256) void head_kernel(
    const unsigned* __restrict__ pooledu, const float* __restrict__ a,
    const float* __restrict__ afc1_w, const float* __restrict__ afc1_b,
    const float* __restrict__ afc2_w, const float* __restrict__ afc2_b,
    const float* __restrict__ afc3_w, const float* __restrict__ afc3_b,
    const float* __restrict__ fc1_w, const float* __restrict__ fc1_b,
    const float* __restrict__ fc2_w, const float* __restrict__ fc2_b,
    const float* __restrict__ ln1_g, const float* __restrict__ ln1_b,
    const float* __restrict__ ln2_g, const float* __restrict__ ln2_b,
    const float* __restrict__ ln4_g, const float* __restrict__ ln4_b,
    const float* __restrict__ ln5_g, const float* __restrict__ ln5_b,
    float* __restrict__ out) {
    __shared__ float red[4];
    __shared__ float sM[2];
    __shared__ float s1[56], s2[56], sZ[256], sT[64];
    int b = blockIdx.x, tid = threadIdx.x;

    float pv = decf(pooledu[(size_t)b * 256 + tid]);
    float m = blk_sum(pv, red) * (1.f / 256.f);
    float d0 = pv - m;
    float var = blk_sum(d0 * d0, red) * (1.f / 256.f);
    float V = d0 * rsqrtf(var + LN_EPS) * ln2_g[tid] + ln2_b[tid];

    if (tid < 56) {
        float acc = afc1_b[tid];
        #pragma unroll
        for (int k = 0; k < 7; ++k) acc += a[b * 7 + k] * afc1_w[k * 56 + tid];
        s1[tid] = leaky(acc);
    }
    __syncthreads();
    if (tid == 0) {
        float s = 0.f; for (int k = 0; k < 56; ++k) s += s1[k];
        float mm = s / 56.f;
        float q = 0.f; for (int k = 0; k < 56; ++k) { float d = s1[k] - mm; q += d * d; }
        sM[0] = mm; sM[1] = rsqrtf(q / 56.f + LN_EPS);
    }
    __syncthreads();
    if (tid < 56) s1[tid] = (s1[tid] - sM[0]) * sM[1] * ln5_g[tid] + ln5_b[tid];
    __syncthreads();
    if (tid < 56) {
        float acc = afc2_b[tid];
        for (int k = 0; k < 56; ++k) acc += s1[k] * afc2_w[k * 56 + tid];
        s2[tid] = leaky(acc);
    }
    __syncthreads();
    float acc = afc3_b[tid];
    for (int k = 0; k < 56; ++k) acc += s2[k] * afc3_w[k * 256 + tid];
    acc = leaky(acc);
    m = blk_sum(acc, red) * (1.f / 256.f);
    d0 = acc - m;
    var = blk_sum(d0 * d0, red) * (1.f / 256.f);
    float av = d0 * rsqrtf(var + LN_EPS) * ln1_g[tid] + ln1_b[tid];

    float z = V * av;
    sZ[tid] = z;
    __syncthreads();
    if (tid < 64) {
        float a2 = fc1_b[tid];
        for (int k = 0; k < 256; ++k) a2 += sZ[k] * fc1_w[k * 64 + tid];
        sT[tid] = leaky(a2);
    }
    __syncthreads();
    if (tid == 0) {
        float s = 0.f; for (int k = 0; k < 64; ++k) s += sT[k];
        float mm = s / 64.f;
        float q = 0.f; for (int k = 0; k < 64; ++k) { float d = sT[k] - mm; q += d * d; }
        float r = rsqrtf(q / 64.f + LN_EPS);
        float o = fc2_b[0];
        for (int k = 0; k < 64; ++k) {
            float zz = (sT[k] - mm) * r * ln4_g[k] + ln4_b[k];
            o += zz * fc2_w[k];
        }
        out[b] = o;
    }
}

// ---------------- launch ----------------

extern "C" void kernel_launch(void* const* d_in, const int* in_sizes, int n_in,
                              void* d_out, int out_size, void* d_ws, size_t ws_size,
                              hipStream_t stream) {
    const float* x     = (const float*)d_in[0];
    const int*   eidx  = (const int*)d_in[1];
    const int*   batch = (const int*)d_in[2];
    const float* a     = (const float*)d_in[3];
    const float* W0 = (const float*)d_in[4];  const float* b0 = (const float*)d_in[5];
    const float* W1 = (const float*)d_in[6];  const float* b1 = (const float*)d_in[7];
    const float* W2 = (const float*)d_in[8];  const float* b2 = (const float*)d_in[9];
    const float* W3 = (const float*)d_in[10]; const float* b3 = (const float*)d_in[11];
    const float* afc1_w = (const float*)d_in[12]; const float* afc1_b = (const float*)d_in[13];
    const float* afc2_w = (const float*)d_in[14]; const float* afc2_b = (const float*)d_in[15];
    const float* afc3_w = (const float*)d_in[16]; const float* afc3_b = (const float*)d_in[17];
    const float* fc1_w  = (const float*)d_in[18]; const float* fc1_b  = (const float*)d_in[19];
    const float* fc2_w  = (const float*)d_in[20]; const float* fc2_b  = (const float*)d_in[21];
    const float* ln1_g = (const float*)d_in[22]; const float* ln1_b = (const float*)d_in[23];
    const float* ln2_g = (const float*)d_in[24]; const float* ln2_b = (const float*)d_in[25];
    const float* ln4_g = (const float*)d_in[26]; const float* ln4_b = (const float*)d_in[27];
    const float* ln5_g = (const float*)d_in[28]; const float* ln5_b = (const float*)d_in[29];

    int N = in_sizes[0] / 3;
    int E = in_sizes[1] / 2;
    int B = in_sizes[3] / 7;
    int Mpad = ((N + 63) / 64) * 64;
    int NB = (N + SCAN_CHUNK - 1) / SCAN_CHUNK;
    int Ecap = E + 7 * N + 8;

    char* p = (char*)d_ws;
    auto alloc = [&](size_t bytes) -> char* {
        char* r = p; p += (bytes + 255) & ~(size_t)255; return r;
    };
    int*   ec   = (int*)alloc((size_t)N * 4);
    int*   fill = (int*)alloc((size_t)N * 4);
    int*   ptr  = (int*)alloc((size_t)(N + 1) * 4);
    int*   bsum = (int*)alloc((size_t)(NB + 1) * 4);
    int*   csrc = (int*)alloc((size_t)Ecap * 4);
    float* dinv = (float*)alloc((size_t)Mpad * 4);
    float4* xp  = (float4*)alloc((size_t)Mpad * 16);
    float* aggx = (float*)alloc((size_t)N * 3 * 4);
    float* h    = (float*)alloc((size_t)Mpad * 256 * 4);
    unsigned short* hbs = (unsigned short*)alloc((size_t)Mpad * 256 * 2);  // [8][Mpad][32]
    unsigned short* agg = (unsigned short*)alloc((size_t)Mpad * 256 * 2);  // [8][Mpad][32]
    unsigned short* wt  = (unsigned short*)alloc((size_t)3 * 65536 * 2);
    unsigned* pooledu = (unsigned*)alloc((size_t)B * 256 * 4);

    const int* srcl = eidx;
    const int* dstl = eidx + E;

    init_kernel<<<(N + 255) / 256, 256, 0, stream>>>(ec, fill, N);
    deg_kernel<<<(E + 255) / 256, 256, 0, stream>>>(dstl, ec, E);
    scanA<<<NB, 256, 0, stream>>>(ec, bsum, N);
    scanB<<<1, 64, 0, stream>>>(bsum, NB);
    scanC<<<NB, 256, 0, stream>>>(ec, bsum, ptr, N, NB);
    dinv_kernel<<<(Mpad + 255) / 256, 256, 0, stream>>>(ec, dinv, N, Mpad);
    xp_kernel<<<(Mpad + 255) / 256, 256, 0, stream>>>(x, dinv, xp, N, Mpad);
    csrc_init_kernel<<<(Ecap + 255) / 256, 256, 0, stream>>>(ptr, csrc, N);
    fill_kernel<<<(E + 255) / 256, 256, 0, stream>>>(srcl, dstl, ptr, fill, csrc, E);
    wt_kernel<<<dim3(256, 3), 256, 0, stream>>>(W1, W2, W3, wt);
    aggx_kernel<<<(N + 255) / 256, 256, 0, stream>>>(xp, dinv, ptr, csrc, aggx, N);
    h0_kernel<<<Mpad / 4, 256, 0, stream>>>(aggx, W0, b0, dinv, h, hbs, N, Mpad);
    pool_init_kernel<<<B, 256, 0, stream>>>(pooledu);

    const float* biases[3] = { b1, b2, b3 };
    int nblkN = (N + 63) / 64;
    for (int l = 0; l < 3; ++l) {
        spmm_kernel<<<nblkN * 8, 256, 0, stream>>>(hbs, ptr, csrc, dinv, agg, N, Mpad);
        gemm_kernel<<<Mpad / 64, 256, 0, stream>>>(agg, wt + (size_t)l * 65536, biases[l],
                                                   dinv, h, hbs, batch, pooledu,
                                                   Mpad, N, (l < 2) ? 1 : 0, (l == 2) ? 1 : 0);
    }

    head_kernel<<<B, 256, 0, stream>>>(pooledu, a,
        afc1_w, afc1_b, afc2_w, afc2_b, afc3_w, afc3_b,
        fc1_w, fc1_b, fc2_w, fc2_b,
        ln1_g, ln1_b, ln2_g, ln2_b, ln4_g, ln4_b, ln5_g, ln5_b,
        (float*)d_out);
}

// Round 8
// 506.122 us; speedup vs baseline: 2.4910x; 1.1089x over previous
//
#include <hip/hip_runtime.h>

#define LN_EPS 1e-5f
#define SCAN_CHUNK 4096

typedef __bf16 bf16x8 __attribute__((ext_vector_type(8)));
typedef float f32x4 __attribute__((ext_vector_type(4)));
typedef float f32x2 __attribute__((ext_vector_type(2)));

__device__ __forceinline__ float b2f(unsigned short s) {
    union { unsigned u; float f; } c; c.u = ((unsigned)s) << 16; return c.f;
}
__device__ __forceinline__ unsigned short f2b(float f) {
    union { float f; unsigned u; } c; c.f = f;
    unsigned r = (c.u + 0x7FFFu + ((c.u >> 16) & 1u)) >> 16;
    return (unsigned short)r;
}
__device__ __forceinline__ f32x2 up2(unsigned u) {
    union { unsigned u; float f; } lo, hi;
    lo.u = u << 16; hi.u = u & 0xffff0000u;
    f32x2 r; r.x = lo.f; r.y = hi.f; return r;
}
__device__ __forceinline__ unsigned pk2(f32x2 v) {
    return ((unsigned)f2b(v.y) << 16) | (unsigned)f2b(v.x);
}
__device__ __forceinline__ float leaky(float x) { return x >= 0.f ? x : 0.01f * x; }
__device__ __forceinline__ unsigned encf(float f) {
    union { float f; unsigned u; } c; c.f = f;
    return ((int)c.u < 0) ? ~c.u : (c.u | 0x80000000u);
}
__device__ __forceinline__ float decf(unsigned u) {
    union { unsigned u; float f; } c;
    c.u = (u & 0x80000000u) ? (u & 0x7FFFFFFFu) : ~u;
    return c.f;
}

// ---------------- CSR build (padded-to-8 edge lists) ----------------

__global__ void init_kernel(int* ec, int* fill, int n) {
    int i = blockIdx.x * 256 + threadIdx.x;
    if (i < n) { ec[i] = 0; fill[i] = 0; }
}

__global__ void deg_kernel(const int* __restrict__ dst, int* ec, int e) {
    int i = blockIdx.x * 256 + threadIdx.x;
    if (i < e) atomicAdd(&ec[dst[i]], 1);
}

__global__ void scanA(const int* __restrict__ ec, int* __restrict__ bsum, int n) {
    __shared__ int red[4];
    int b = blockIdx.x, t = threadIdx.x;
    int base = b * SCAN_CHUNK + t * 16;
    int s = 0;
    #pragma unroll
    for (int k = 0; k < 16; ++k) { int i = base + k; if (i < n) s += (ec[i] + 7) & ~7; }
    #pragma unroll
    for (int off = 32; off; off >>= 1) s += __shfl_down(s, off, 64);
    if ((t & 63) == 0) red[t >> 6] = s;
    __syncthreads();
    if (t == 0) bsum[b] = red[0] + red[1] + red[2] + red[3];
}

__global__ void scanB(int* bsum, int nb) {
    if (threadIdx.x == 0) {
        int acc = 0;
        for (int i = 0; i < nb; ++i) { int v = bsum[i]; bsum[i] = acc; acc += v; }
        bsum[nb] = acc;
    }
}

__global__ void scanC(const int* __restrict__ ec, const int* __restrict__ bsum,
                      int* __restrict__ ptr, int n, int nb) {
    __shared__ int wsum[4];
    int b = blockIdx.x, t = threadIdx.x, lane = t & 63, w = t >> 6;
    int base = b * SCAN_CHUNK + t * 16;
    int loc[16]; int s = 0;
    #pragma unroll
    for (int k = 0; k < 16; ++k) {
        int i = base + k; int v = (i < n) ? ((ec[i] + 7) & ~7) : 0;
        loc[k] = s; s += v;
    }
    int x = s;
    #pragma unroll
    for (int off = 1; off < 64; off <<= 1) { int y = __shfl_up(x, off, 64); if (lane >= off) x += y; }
    if (lane == 63) wsum[w] = x;
    __syncthreads();
    int wexcl = 0;
    #pragma unroll
    for (int ww = 0; ww < 4; ++ww) if (ww < w) wexcl += wsum[ww];
    int toff = bsum[b] + wexcl + (x - s);
    #pragma unroll
    for (int k = 0; k < 16; ++k) { int i = base + k; if (i < n) ptr[i] = toff + loc[k]; }
    if (b == nb - 1 && t == 255) ptr[n] = bsum[nb];
}

// dinv/sdeg/xp + fill pad slots of csrc with zero-row offset
__global__ void node_setup(const float* __restrict__ x, const int* __restrict__ ec,
                           const int* __restrict__ ptr,
                           float* __restrict__ dinv, float* __restrict__ sdeg,
                           float4* __restrict__ xp, int* __restrict__ csrc,
                           int n, int mpad) {
    int i = blockIdx.x * 256 + threadIdx.x;
    if (i >= mpad) return;
    float dv = 0.f, sv = 0.f;
    float4 v = make_float4(0.f, 0.f, 0.f, 0.f);
    if (i < n) {
        int e = ec[i];
        float dg = (float)(e + 1);
        dv = rsqrtf(dg); sv = sqrtf(dg);
        v.x = dv * x[i * 3]; v.y = dv * x[i * 3 + 1]; v.z = dv * x[i * 3 + 2];
        int p0 = ptr[i] + e, p1 = ptr[i] + ((e + 7) & ~7);
        int pad = n << 6;
        for (int j = p0; j < p1; ++j) csrc[j] = pad;
    }
    dinv[i] = dv; sdeg[i] = sv; xp[i] = v;
}

__global__ void fill_kernel(const int* __restrict__ src, const int* __restrict__ dst,
                            const int* __restrict__ ptr, int* fill,
                            int* __restrict__ csrc, int e) {
    int i = blockIdx.x * 256 + threadIdx.x;
    if (i < e) {
        int d = dst[i];
        int pos = atomicAdd(&fill[d], 1);
        csrc[ptr[d] + pos] = src[i] << 6;   // pre-shifted byte offset (64B rows)
    }
}

// ---------------- weights: W^T in bf16 ----------------

__global__ void wt_kernel(const float* __restrict__ W1, const float* __restrict__ W2,
                          const float* __restrict__ W3, unsigned short* __restrict__ wt) {
    int k = blockIdx.x, l = blockIdx.y, nn = threadIdx.x;
    const float* W = (l == 0) ? W1 : (l == 1) ? W2 : W3;
    wt[l * 65536 + nn * 256 + k] = f2b(W[k * 256 + nn]);
}

// ---------------- layer 0 ----------------

__global__ void aggx_kernel(const float4* __restrict__ xp, const float* __restrict__ dinv,
                            const int* __restrict__ ptr, const int* __restrict__ csrc,
                            float* __restrict__ aggx, int n) {
    int i = blockIdx.x * 256 + threadIdx.x;
    if (i >= n) return;
    const char* xb = (const char*)xp;
    float4 self = xp[i];
    float a0 = self.x, a1 = self.y, a2 = self.z;
    float p0 = 0.f, p1 = 0.f, p2 = 0.f;
    float q0 = 0.f, q1 = 0.f, q2 = 0.f;
    float r0 = 0.f, r1 = 0.f, r2 = 0.f;
    int e0 = ptr[i], e1 = ptr[i + 1];
    for (int e = e0; e < e1; e += 4) {
        int4 v = *(const int4*)(csrc + e);
        float4 u0 = *(const float4*)(xb + (((unsigned)v.x) >> 2));
        float4 u1 = *(const float4*)(xb + (((unsigned)v.y) >> 2));
        float4 u2 = *(const float4*)(xb + (((unsigned)v.z) >> 2));
        float4 u3 = *(const float4*)(xb + (((unsigned)v.w) >> 2));
        a0 += u0.x; a1 += u0.y; a2 += u0.z;
        p0 += u1.x; p1 += u1.y; p2 += u1.z;
        q0 += u2.x; q1 += u2.y; q2 += u2.z;
        r0 += u3.x; r1 += u3.y; r2 += u3.z;
    }
    a0 += (p0 + q0) + r0; a1 += (p1 + q1) + r1; a2 += (p2 + q2) + r2;
    float di = dinv[i];
    aggx[i * 3] = a0 * di; aggx[i * 3 + 1] = a1 * di; aggx[i * 3 + 2] = a2 * di;
}

// h0 = aggx @ W0 + b0; hbs = bf16(dinv*h0) chunked [8][mpad][32], zero pad rows
__global__ __launch_bounds__(256) void h0_kernel(const float* __restrict__ aggx,
                          const float* __restrict__ W0, const float* __restrict__ b0,
                          const float* __restrict__ dinv,
                          unsigned short* __restrict__ hbs,
                          int n, int mpad) {
    int t = threadIdx.x;
    int row = blockIdx.x * 4 + (t >> 6);
    int f = (t & 63) * 4;
    if (row >= mpad) return;
    unsigned short* hp = hbs + ((size_t)(f >> 5) * mpad + row) * 32 + (f & 31);
    if (row < n) {
        float a0 = aggx[row * 3], a1 = aggx[row * 3 + 1], a2 = aggx[row * 3 + 2];
        float4 w0 = *(const float4*)(W0 + f);
        float4 w1 = *(const float4*)(W0 + 256 + f);
        float4 w2 = *(const float4*)(W0 + 512 + f);
        float4 bb = *(const float4*)(b0 + f);
        float4 v;
        v.x = bb.x + a0 * w0.x + a1 * w1.x + a2 * w2.x;
        v.y = bb.y + a0 * w0.y + a1 * w1.y + a2 * w2.y;
        v.z = bb.z + a0 * w0.z + a1 * w1.z + a2 * w2.z;
        v.w = bb.w + a0 * w0.w + a1 * w1.w + a2 * w2.w;
        float di = dinv[row];
        ushort4 o;
        o.x = f2b(di * v.x); o.y = f2b(di * v.y); o.z = f2b(di * v.z); o.w = f2b(di * v.w);
        *(ushort4*)hp = o;
    } else {
        ushort4 o; o.x = 0; o.y = 0; o.z = 0; o.w = 0;
        *(ushort4*)hp = o;
    }
}

// ---------------- SpMM pure gather, padded lists, dwordx4 payloads ----------------

__global__ __launch_bounds__(256) void spmm_kernel(
    const unsigned short* __restrict__ hbs,
    const int* __restrict__ ptr, const int* __restrict__ csrc,
    const float* __restrict__ dinv,
    unsigned short* __restrict__ agg,
    int n, int mpad) {
    int chunk = blockIdx.x & 7;   // chunk pinned to XCD (round-robin dispatch)
    int g = blockIdx.x >> 3;
    int t = threadIdx.x;
    int node = g * 64 + (t >> 2);
    if (node >= n) return;
    unsigned loff = (unsigned)((t & 3) << 4);
    const char* cb = (const char*)hbs + (size_t)chunk * mpad * 64;
    int e0 = ptr[node], e1 = ptr[node + 1];
    uint4 own = *(const uint4*)(cb + (((unsigned)node << 6) | loff));
    f32x2 accA0 = up2(own.x), accA1 = up2(own.y), accA2 = up2(own.z), accA3 = up2(own.w);
    f32x2 accB0 = (f32x2)(0.f), accB1 = (f32x2)(0.f), accB2 = (f32x2)(0.f), accB3 = (f32x2)(0.f);
    int e = e0;
    int4 ia, ib;
    if (e < e1) { ia = *(const int4*)(csrc + e); ib = *(const int4*)(csrc + e + 4); }
    while (e < e1) {
        int en = e + 8;
        int4 na, nb;
        if (en < e1) { na = *(const int4*)(csrc + en); nb = *(const int4*)(csrc + en + 4); }
        uint4 u0 = *(const uint4*)(cb + ((unsigned)ia.x | loff));
        uint4 u1 = *(const uint4*)(cb + ((unsigned)ia.y | loff));
        uint4 u2 = *(const uint4*)(cb + ((unsigned)ia.z | loff));
        uint4 u3 = *(const uint4*)(cb + ((unsigned)ia.w | loff));
        uint4 u4 = *(const uint4*)(cb + ((unsigned)ib.x | loff));
        uint4 u5 = *(const uint4*)(cb + ((unsigned)ib.y | loff));
        uint4 u6 = *(const uint4*)(cb + ((unsigned)ib.z | loff));
        uint4 u7 = *(const uint4*)(cb + ((unsigned)ib.w | loff));
        accA0 += up2(u0.x); accA1 += up2(u0.y); accA2 += up2(u0.z); accA3 += up2(u0.w);
        accB0 += up2(u1.x); accB1 += up2(u1.y); accB2 += up2(u1.z); accB3 += up2(u1.w);
        accA0 += up2(u2.x); accA1 += up2(u2.y); accA2 += up2(u2.z); accA3 += up2(u2.w);
        accB0 += up2(u3.x); accB1 += up2(u3.y); accB2 += up2(u3.z); accB3 += up2(u3.w);
        accA0 += up2(u4.x); accA1 += up2(u4.y); accA2 += up2(u4.z); accA3 += up2(u4.w);
        accB0 += up2(u5.x); accB1 += up2(u5.y); accB2 += up2(u5.z); accB3 += up2(u5.w);
        accA0 += up2(u6.x); accA1 += up2(u6.y); accA2 += up2(u6.z); accA3 += up2(u6.w);
        accB0 += up2(u7.x); accB1 += up2(u7.y); accB2 += up2(u7.z); accB3 += up2(u7.w);
        ia = na; ib = nb; e = en;
    }
    float di = dinv[node];
    f32x2 dd; dd.x = di; dd.y = di;
    accA0 = (accA0 + accB0) * dd;
    accA1 = (accA1 + accB1) * dd;
    accA2 = (accA2 + accB2) * dd;
    accA3 = (accA3 + accB3) * dd;
    uint4 o;
    o.x = pk2(accA0); o.y = pk2(accA1); o.z = pk2(accA2); o.w = pk2(accA3);
    *(uint4*)((char*)agg + (size_t)chunk * mpad * 64 + (((unsigned)node << 6) | loff)) = o;
}

// ---------------- GEMM + fused epilogue (residual in bf16 hbs only) ----------------
// layers 1,2: v = leaky(agg@W + bias) + b2f(hbs)*sdeg; hbs = f2b(v*dinv)
// layer 3 (last): v = leaky(..) + b2f(hbs)*sdeg, atomicMax(pooled) per segment

__global__ __launch_bounds__(256) void gemm_kernel(const unsigned short* __restrict__ A,
                                                   const unsigned short* __restrict__ Bt,
                                                   const float* __restrict__ bias,
                                                   const float* __restrict__ dinv,
                                                   const float* __restrict__ sdeg,
                                                   unsigned short* __restrict__ hbs,
                                                   const int* __restrict__ batch,
                                                   unsigned* __restrict__ pooledu,
                                                   int mpad, int n, int last) {
    const int K = 256;
    __shared__ int sb[64];
    int wid = threadIdx.x >> 6, lane = threadIdx.x & 63;
    int m0 = blockIdx.x * 64;
    if (last && threadIdx.x < 64) {
        int r = m0 + threadIdx.x;
        sb[threadIdx.x] = (r < n) ? batch[r] : -1;
    }
    __syncthreads();
    int n0 = wid * 64;
    int lr = lane & 15, lg = lane >> 4;
    f32x4 acc[4][4];
    #pragma unroll
    for (int i = 0; i < 4; i++)
        #pragma unroll
        for (int j = 0; j < 4; j++) acc[i][j] = (f32x4)(0.f);
    const unsigned short* Ap = A + ((size_t)(m0 + lr)) * 32 + lg * 8;
    const unsigned short* Bp = Bt + (size_t)(n0 + lr) * K + lg * 8;
    #pragma unroll
    for (int kc = 0; kc < 8; ++kc) {
        bf16x8 af[4], bfr[4];
        #pragma unroll
        for (int mi = 0; mi < 4; mi++)
            af[mi] = *(const bf16x8*)(Ap + (size_t)kc * mpad * 32 + mi * 512);
        #pragma unroll
        for (int ni = 0; ni < 4; ni++)
            bfr[ni] = *(const bf16x8*)(Bp + (size_t)ni * 16 * K + kc * 32);
        #pragma unroll
        for (int mi = 0; mi < 4; mi++)
            #pragma unroll
            for (int ni = 0; ni < 4; ni++)
                acc[mi][ni] = __builtin_amdgcn_mfma_f32_16x16x32_bf16(af[mi], bfr[ni], acc[mi][ni], 0, 0, 0);
    }
    if (!last) {
        #pragma unroll
        for (int mi = 0; mi < 4; mi++) {
            int r0 = m0 + mi * 16 + lg * 4;
            float4 dv = *(const float4*)(dinv + r0);
            float4 sv = *(const float4*)(sdeg + r0);
            #pragma unroll
            for (int ni = 0; ni < 4; ni++) {
                int c = n0 + ni * 16 + lr;
                float bv = bias[c];
                int ch = c >> 5, cf = c & 31;
                unsigned short* hp = hbs + ((size_t)ch * mpad + r0) * 32 + cf;
                float h0o = b2f(hp[0])  * sv.x;
                float h1o = b2f(hp[32]) * sv.y;
                float h2o = b2f(hp[64]) * sv.z;
                float h3o = b2f(hp[96]) * sv.w;
                float v0 = leaky(acc[mi][ni][0] + bv) + h0o;
                float v1 = leaky(acc[mi][ni][1] + bv) + h1o;
                float v2 = leaky(acc[mi][ni][2] + bv) + h2o;
                float v3 = leaky(acc[mi][ni][3] + bv) + h3o;
                hp[0]  = f2b(v0 * dv.x);
                hp[32] = f2b(v1 * dv.y);
                hp[64] = f2b(v2 * dv.z);
                hp[96] = f2b(v3 * dv.w);
            }
        }
    } else {
        #pragma unroll
        for (int ni = 0; ni < 4; ni++) {
            int c = n0 + ni * 16 + lr;
            float bv = bias[c];
            int ch = c >> 5, cf = c & 31;
            const unsigned short* hpb = hbs + (size_t)ch * mpad * 32 + cf;
            int cs = -1; float cm = 0.f;
            #pragma unroll
            for (int mi = 0; mi < 4; mi++) {
                int rb = mi * 16 + lg * 4;
                #pragma unroll
                for (int j = 0; j < 4; ++j) {
                    int row = m0 + rb + j;
                    int seg = sb[rb + j];
                    float ho = b2f(hpb[(size_t)row * 32]) * sdeg[row];
                    float v = leaky(acc[mi][ni][j] + bv) + ho;
                    if (seg >= 0) {
                        if (seg != cs) {
                            if (cs >= 0) atomicMax(pooledu + (size_t)cs * 256 + c, encf(cm));
                            cs = seg; cm = v;
                        } else {
                            cm = fmaxf(cm, v);
                        }
                    }
                }
            }
            if (cs >= 0) atomicMax(pooledu + (size_t)cs * 256 + c, encf(cm));
        }
    }
}

__global__ void pool_init_kernel(unsigned* pooledu) {
    pooledu[blockIdx.x * 256 + threadIdx.x] = 0u;
}

// ---------------- head ----------------

__device__ __forceinline__ float blk_sum(float v, float* red) {
    #pragma unroll
    for (int off = 32; off; off >>= 1) v += __shfl_down(v, off, 64);
    int lane = threadIdx.x & 63, wid = threadIdx.x >> 6;
    if (lane == 0) red[wid] = v;
    __syncthreads();
    float s = red[0] + red[1] + red[2] + red[3];
    __syncthreads();
    return s;
}

__global__ __launch_bounds__(256) void head_kernel(
    const unsigned* __restrict__ pooledu, const float* __restrict__ a,
    const float* __restrict__ afc1_w, const float* __restrict__ afc1_b,
    const float* __restrict__ afc2_w, const float* __restrict__ afc2_b,
    const float* __restrict__ afc3_w, const float* __restrict__ afc3_b,
    const float* __restrict__ fc1_w, const float* __restrict__ fc1_b,
    const float* __restrict__ fc2_w, const float* __restrict__ fc2_b,
    const float* __restrict__ ln1_g, const float* __restrict__ ln1_b,
    const float* __restrict__ ln2_g, const float* __restrict__ ln2_b,
    const float* __restrict__ ln4_g, const float* __restrict__ ln4_b,
    const float* __restrict__ ln5_g, const float* __restrict__ ln5_b,
    float* __restrict__ out) {
    __shared__ float red[4];
    __shared__ float sM[2];
    __shared__ float s1[56], s2[56], sZ[256], sT[64];
    int b = blockIdx.x, tid = threadIdx.x;

    float pv = decf(pooledu[(size_t)b * 256 + tid]);
    float m = blk_sum(pv, red) * (1.f / 256.f);
    float d0 = pv - m;
    float var = blk_sum(d0 * d0, red) * (1.f / 256.f);
    float V = d0 * rsqrtf(var + LN_EPS) * ln2_g[tid] + ln2_b[tid];

    if (tid < 56) {
        float acc = afc1_b[tid];
        #pragma unroll
        for (int k = 0; k < 7; ++k) acc += a[b * 7 + k] * afc1_w[k * 56 + tid];
        s1[tid] = leaky(acc);
    }
    __syncthreads();
    if (tid == 0) {
        float s = 0.f; for (int k = 0; k < 56; ++k) s += s1[k];
        float mm = s / 56.f;
        float q = 0.f; for (int k = 0; k < 56; ++k) { float d = s1[k] - mm; q += d * d; }
        sM[0] = mm; sM[1] = rsqrtf(q / 56.f + LN_EPS);
    }
    __syncthreads();
    if (tid < 56) s1[tid] = (s1[tid] - sM[0]) * sM[1] * ln5_g[tid] + ln5_b[tid];
    __syncthreads();
    if (tid < 56) {
        float acc = afc2_b[tid];
        for (int k = 0; k < 56; ++k) acc += s1[k] * afc2_w[k * 56 + tid];
        s2[tid] = leaky(acc);
    }
    __syncthreads();
    float acc = afc3_b[tid];
    for (int k = 0; k < 56; ++k) acc += s2[k] * afc3_w[k * 256 + tid];
    acc = leaky(acc);
    m = blk_sum(acc, red) * (1.f / 256.f);
    d0 = acc - m;
    var = blk_sum(d0 * d0, red) * (1.f / 256.f);
    float av = d0 * rsqrtf(var + LN_EPS) * ln1_g[tid] + ln1_b[tid];

    float z = V * av;
    sZ[tid] = z;
    __syncthreads();
    if (tid < 64) {
        float a2 = fc1_b[tid];
        for (int k = 0; k < 256; ++k) a2 += sZ[k] * fc1_w[k * 64 + tid];
        sT[tid] = leaky(a2);
    }
    __syncthreads();
    if (tid == 0) {
        float s = 0.f; for (int k = 0; k < 64; ++k) s += sT[k];
        float mm = s / 64.f;
        float q = 0.f; for (int k = 0; k < 64; ++k) { float d = sT[k] - mm; q += d * d; }
        float r = rsqrtf(q / 64.f + LN_EPS);
        float o = fc2_b[0];
        for (int k = 0; k < 64; ++k) {
            float zz = (sT[k] - mm) * r * ln4_g[k] + ln4_b[k];
            o += zz * fc2_w[k];
        }
        out[b] = o;
    }
}

// ---------------- launch ----------------

extern "C" void kernel_launch(void* const* d_in, const int* in_sizes, int n_in,
                              void* d_out, int out_size, void* d_ws, size_t ws_size,
                              hipStream_t stream) {
    const float* x     = (const float*)d_in[0];
    const int*   eidx  = (const int*)d_in[1];
    const int*   batch = (const int*)d_in[2];
    const float* a     = (const float*)d_in[3];
    const float* W0 = (const float*)d_in[4];  const float* b0 = (const float*)d_in[5];
    const float* W1 = (const float*)d_in[6];  const float* b1 = (const float*)d_in[7];
    const float* W2 = (const float*)d_in[8];  const float* b2 = (const float*)d_in[9];
    const float* W3 = (const float*)d_in[10]; const float* b3 = (const float*)d_in[11];
    const float* afc1_w = (const float*)d_in[12]; const float* afc1_b = (const float*)d_in[13];
    const float* afc2_w = (const float*)d_in[14]; const float* afc2_b = (const float*)d_in[15];
    const float* afc3_w = (const float*)d_in[16]; const float* afc3_b = (const float*)d_in[17];
    const float* fc1_w  = (const float*)d_in[18]; const float* fc1_b  = (const float*)d_in[19];
    const float* fc2_w  = (const float*)d_in[20]; const float* fc2_b  = (const float*)d_in[21];
    const float* ln1_g = (const float*)d_in[22]; const float* ln1_b = (const float*)d_in[23];
    const float* ln2_g = (const float*)d_in[24]; const float* ln2_b = (const float*)d_in[25];
    const float* ln4_g = (const float*)d_in[26]; const float* ln4_b = (const float*)d_in[27];
    const float* ln5_g = (const float*)d_in[28]; const float* ln5_b = (const float*)d_in[29];

    int N = in_sizes[0] / 3;
    int E = in_sizes[1] / 2;
    int B = in_sizes[3] / 7;
    int Mpad = ((N + 63) / 64) * 64;
    int NB = (N + SCAN_CHUNK - 1) / SCAN_CHUNK;
    int Ecap = E + 7 * N + 8;

    char* p = (char*)d_ws;
    auto alloc = [&](size_t bytes) -> char* {
        char* r = p; p += (bytes + 255) & ~(size_t)255; return r;
    };
    int*   ec   = (int*)alloc((size_t)N * 4);
    int*   fill = (int*)alloc((size_t)N * 4);
    int*   ptr  = (int*)alloc((size_t)(N + 1) * 4);
    int*   bsum = (int*)alloc((size_t)(NB + 1) * 4);
    int*   csrc = (int*)alloc((size_t)Ecap * 4);
    float* dinv = (float*)alloc((size_t)Mpad * 4);
    float* sdeg = (float*)alloc((size_t)Mpad * 4);
    float4* xp  = (float4*)alloc((size_t)Mpad * 16);
    float* aggx = (float*)alloc((size_t)N * 3 * 4);
    unsigned short* hbs = (unsigned short*)alloc((size_t)Mpad * 256 * 2);  // [8][Mpad][32]
    unsigned short* agg = (unsigned short*)alloc((size_t)Mpad * 256 * 2);  // [8][Mpad][32]
    unsigned short* wt  = (unsigned short*)alloc((size_t)3 * 65536 * 2);
    unsigned* pooledu = (unsigned*)alloc((size_t)B * 256 * 4);

    const int* srcl = eidx;
    const int* dstl = eidx + E;

    init_kernel<<<(N + 255) / 256, 256, 0, stream>>>(ec, fill, N);
    deg_kernel<<<(E + 255) / 256, 256, 0, stream>>>(dstl, ec, E);
    scanA<<<NB, 256, 0, stream>>>(ec, bsum, N);
    scanB<<<1, 64, 0, stream>>>(bsum, NB);
    scanC<<<NB, 256, 0, stream>>>(ec, bsum, ptr, N, NB);
    node_setup<<<(Mpad + 255) / 256, 256, 0, stream>>>(x, ec, ptr, dinv, sdeg, xp, csrc, N, Mpad);
    fill_kernel<<<(E + 255) / 256, 256, 0, stream>>>(srcl, dstl, ptr, fill, csrc, E);
    wt_kernel<<<dim3(256, 3), 256, 0, stream>>>(W1, W2, W3, wt);
    aggx_kernel<<<(N + 255) / 256, 256, 0, stream>>>(xp, dinv, ptr, csrc, aggx, N);
    h0_kernel<<<Mpad / 4, 256, 0, stream>>>(aggx, W0, b0, dinv, hbs, N, Mpad);
    pool_init_kernel<<<B, 256, 0, stream>>>(pooledu);

    const float* biases[3] = { b1, b2, b3 };
    int nblkN = (N + 63) / 64;
    for (int l = 0; l < 3; ++l) {
        spmm_kernel<<<nblkN * 8, 256, 0, stream>>>(hbs, ptr, csrc, dinv, agg, N, Mpad);
        gemm_kernel<<<Mpad / 64, 256, 0, stream>>>(agg, wt + (size_t)l * 65536, biases[l],
                                                   dinv, sdeg, hbs, batch, pooledu,
                                                   Mpad, N, (l == 2) ? 1 : 0);
    }

    head_kernel<<<B, 256, 0, stream>>>(pooledu, a,
        afc1_w, afc1_b, afc2_w, afc2_b, afc3_w, afc3_b,
        fc1_w, fc1_b, fc2_w, fc2_b,
        ln1_g, ln1_b, ln2_g, ln2_b, ln4_g, ln4_b, ln5_g, ln5_b,
        (float*)d_out);
}